// Round 4
// baseline (660.673 us; speedup 1.0000x reference)
//
#include <hip/hip_runtime.h>
#include <math.h>

// Problem constants (match reference)
#define N_NODES 20000
#define N_EDGES 320000
#define D_IN    512
#define D_HID   128
#define N_HEADS 8
#define N_CLS   64

typedef __bf16 bf16x8 __attribute__((ext_vector_type(8)));
typedef float  f32x4  __attribute__((ext_vector_type(4)));

__device__ __forceinline__ float leaky(float x) { return fmaxf(x, 0.01f * x); }

// fp32 -> bf16 round-to-nearest-even
__device__ __forceinline__ unsigned short f2bf(float f) {
    unsigned u = __float_as_uint(f);
    return (unsigned short)((u + 0x7FFFu + ((u >> 16) & 1u)) >> 16);
}
__device__ __forceinline__ float bflo(unsigned v) { return __uint_as_float(v << 16); }
__device__ __forceinline__ float bfhi(unsigned v) { return __uint_as_float(v & 0xffff0000u); }

__device__ __forceinline__ void gl_lds16(const void* g, void* l) {
    __builtin_amdgcn_global_load_lds((const __attribute__((address_space(1))) void*)g,
                                     (__attribute__((address_space(3))) void*)l, 16, 0, 0);
}

// ---------------- CSR build (rebuilt every call) ----------------
__global__ void k_zero(int* __restrict__ p, int n) {
    int i = blockIdx.x * blockDim.x + threadIdx.x;
    if (i < n) p[i] = 0;
}

__global__ void k_count(const int* __restrict__ dst, int* __restrict__ counts, int e) {
    int i = blockIdx.x * blockDim.x + threadIdx.x;
    if (i < e) atomicAdd(&counts[dst[i]], 1);
}

__global__ void k_scan(const int* __restrict__ counts, int* __restrict__ indptr,
                       int* __restrict__ cursor, int n) {
    __shared__ int sdata[1024];
    __shared__ int srun;
    int t = threadIdx.x;
    if (t == 0) srun = 0;
    __syncthreads();
    for (int base = 0; base < n; base += 1024) {
        int idx = base + t;
        int v = (idx < n) ? counts[idx] : 0;
        sdata[t] = v;
        __syncthreads();
        for (int off = 1; off < 1024; off <<= 1) {
            int x = (t >= off) ? sdata[t - off] : 0;
            __syncthreads();
            sdata[t] += x;
            __syncthreads();
        }
        int incl = sdata[t];
        int run = srun;
        if (idx < n) {
            indptr[idx] = run + incl - v;
            cursor[idx] = run + incl - v;
        }
        __syncthreads();
        if (t == 1023) srun = run + incl;
        __syncthreads();
    }
    if (t == 0) indptr[n] = srun;
}

__global__ void k_scatter(const int* __restrict__ src, const int* __restrict__ dst,
                          int* __restrict__ cursor, int* __restrict__ csr_src, int e) {
    int i = blockIdx.x * blockDim.x + threadIdx.x;
    if (i < e) {
        int pos = atomicAdd(&cursor[dst[i]], 1);
        csr_src[pos] = src[i];
    }
}

// ---------------- conversions ----------------
__global__ void k_cvtA(const float* __restrict__ in, unsigned short* __restrict__ out, int n4) {
    int i = blockIdx.x * blockDim.x + threadIdx.x;
    if (i < n4) {
        float4 v = ((const float4*)in)[i];
        unsigned long long pk =
            (unsigned long long)f2bf(v.x) | ((unsigned long long)f2bf(v.y) << 16) |
            ((unsigned long long)f2bf(v.z) << 32) | ((unsigned long long)f2bf(v.w) << 48);
        *(unsigned long long*)(out + (size_t)i * 4) = pk;
    }
}

// W [h][K][Nf] fp32 -> Wt [h][Nf][K] bf16
__global__ void k_cvtW(const float* __restrict__ W, unsigned short* __restrict__ Wt,
                       int K, int Nf) {
    __shared__ float t[64][65];
    int k0 = blockIdx.x * 64, n0 = blockIdx.y * 64, h = blockIdx.z;
    const float* Wh = W + (size_t)h * K * Nf;
    unsigned short* Wth = Wt + (size_t)h * K * Nf;
    int tx = threadIdx.x & 63, ty = threadIdx.x >> 6;
#pragma unroll
    for (int i = 0; i < 16; ++i) {
        int k = ty + i * 4;
        t[k][tx] = Wh[(size_t)(k0 + k) * Nf + n0 + tx];
    }
    __syncthreads();
#pragma unroll
    for (int i = 0; i < 16; ++i) {
        int n = ty + i * 4;
        Wth[(size_t)(n0 + n) * K + k0 + tx] = f2bf(t[tx][n]);
    }
}

// ---------------- bf16 MFMA GEMM, bf16 output ----------------
// C[h*strideCh + m*ldc + n] (bf16) = A[m,:K](bf16) @ Bt_h[n,:K](bf16)^T + bias_h[n]
template<int BN>
__global__ __launch_bounds__(256) void k_gemm_bf16(
    const unsigned short* __restrict__ A, const unsigned short* __restrict__ Bt,
    const float* __restrict__ bias, unsigned short* __restrict__ C,
    int M, int K, int ldc, long strideCh)
{
    constexpr int BM = 128, BK = 64;
    constexpr int WN    = (BN == 128) ? 2 : 1;
    constexpr int MFRAG = (BN == 128) ? 4 : 2;
    constexpr int NFRAG = 4;

    __shared__ unsigned short As[BM * BK];
    __shared__ unsigned short Bs[BN * BK];

    const int tid  = threadIdx.x;
    const int lane = tid & 63;
    const int wid  = tid >> 6;
    const int wm   = wid / WN;
    const int wn   = wid % WN;
    const int m0   = blockIdx.x * BM;
    const int h    = blockIdx.z;

    const unsigned short* Bth = Bt + (size_t)h * BN * K;
    const float* biash = bias + h * BN;
    unsigned short* Ch = C + (size_t)h * strideCh;

    const int rsub = lane & 15;
    const int rhi  = lane >> 4;
    const int wbase = (tid & ~63);

    f32x4 acc[MFRAG][NFRAG];
#pragma unroll
    for (int i = 0; i < MFRAG; ++i)
#pragma unroll
        for (int j = 0; j < NFRAG; ++j) acc[i][j] = (f32x4){0.f, 0.f, 0.f, 0.f};

    for (int k0 = 0; k0 < K; k0 += BK) {
#pragma unroll
        for (int p = 0; p < 4; ++p) {
            int o    = (p * 256 + tid) * 16;
            int row  = o >> 7;
            int icol = (o & 127) ^ ((row & 7) << 4);
            int grow = m0 + row; if (grow > M - 1) grow = M - 1;
            gl_lds16(A + (size_t)grow * K + k0 + (icol >> 1),
                     (void*)((char*)As + (p * 256 + wbase) * 16));
        }
#pragma unroll
        for (int p = 0; p < BN / 32; ++p) {
            int o    = (p * 256 + tid) * 16;
            int row  = o >> 7;
            int icol = (o & 127) ^ ((row & 7) << 4);
            gl_lds16(Bth + (size_t)row * K + k0 + (icol >> 1),
                     (void*)((char*)Bs + (p * 256 + wbase) * 16));
        }
        __syncthreads();

        bf16x8 av[2][MFRAG], bv[2][NFRAG];
#pragma unroll
        for (int q = 0; q < 2; ++q) {
#pragma unroll
            for (int mi = 0; mi < MFRAG; ++mi) {
                int row  = wm * (MFRAG * 16) + mi * 16 + rsub;
                int icol = (q * 64 + rhi * 16) ^ ((row & 7) << 4);
                av[q][mi] = *(const bf16x8*)((const char*)As + row * 128 + icol);
            }
#pragma unroll
            for (int ni = 0; ni < NFRAG; ++ni) {
                int row  = wn * (NFRAG * 16) + ni * 16 + rsub;
                int icol = (q * 64 + rhi * 16) ^ ((row & 7) << 4);
                bv[q][ni] = *(const bf16x8*)((const char*)Bs + row * 128 + icol);
            }
        }
#pragma unroll
        for (int q = 0; q < 2; ++q)
#pragma unroll
            for (int mi = 0; mi < MFRAG; ++mi)
#pragma unroll
                for (int ni = 0; ni < NFRAG; ++ni)
                    acc[mi][ni] = __builtin_amdgcn_mfma_f32_16x16x32_bf16(
                        av[q][mi], bv[q][ni], acc[mi][ni], 0, 0, 0);
        __syncthreads();
    }

    // epilogue: C/D layout col=lane&15, row=(lane>>4)*4+reg; write bf16
#pragma unroll
    for (int ni = 0; ni < NFRAG; ++ni) {
        int col  = wn * (NFRAG * 16) + ni * 16 + rsub;
        float bvv = biash[col];
#pragma unroll
        for (int mi = 0; mi < MFRAG; ++mi) {
            int rowb = m0 + wm * (MFRAG * 16) + mi * 16 + rhi * 4;
#pragma unroll
            for (int r = 0; r < 4; ++r) {
                int row = rowb + r;
                if (row < M) Ch[(size_t)row * ldc + col] = f2bf(acc[mi][ni][r] + bvv);
            }
        }
    }
}

// ---------------- per-node attention logits (bf16 ft, [h][N][Dh] layout) ----------------
__global__ __launch_bounds__(256) void k_alogit(
    const unsigned short* __restrict__ ft, const float* __restrict__ al,
    const float* __restrict__ alb, const float* __restrict__ ar,
    const float* __restrict__ arb, float* __restrict__ a1,
    float* __restrict__ a2, int H_, int Dh)
{
    int n = blockIdx.x * 4 + (threadIdx.x >> 6);
    int lane = threadIdx.x & 63;
    if (n >= N_NODES) return;
    for (int h = 0; h < H_; ++h) {
        size_t base = ((size_t)h * N_NODES + n) * Dh;
        float s1 = 0.f, s2 = 0.f;
        for (int j0 = 2 * lane; j0 < Dh; j0 += 128) {
            unsigned v = *(const unsigned*)(ft + base + j0);
            float lo = bflo(v), hi = bfhi(v);
            float2 A = *(const float2*)(al + h * Dh + j0);
            float2 R = *(const float2*)(ar + h * Dh + j0);
            s1 += lo * A.x + hi * A.y;
            s2 += lo * R.x + hi * R.y;
        }
#pragma unroll
        for (int off = 32; off > 0; off >>= 1) {
            s1 += __shfl_xor(s1, off);
            s2 += __shfl_xor(s2, off);
        }
        if (lane == 0) {
            a1[n * H_ + h] = s1 + alb[h];
            a2[n * H_ + h] = s2 + arb[h];
        }
    }
}

// ---------------- hidden-layer aggregate: H=8, Dh=128, bf16 in [h][N][128], bf16 out [N][1024]
// head = blockIdx.x & 7  => with round-robin block->XCD dispatch, each XCD gathers
// from a single 5.1 MB head slab (~fits its 4 MB L2).
// Quarter-wave gathers: 16 lanes x uint4 = one 256B row; 4 edges in flight.
__global__ __launch_bounds__(256) void k_aggregate8(
    const unsigned short* __restrict__ ft, const float* __restrict__ a1,
    const float* __restrict__ a2, const int* __restrict__ indptr,
    const int* __restrict__ csr_src, unsigned short* __restrict__ outp)
{
    int h = blockIdx.x & 7;
    int n = (blockIdx.x >> 3) * 4 + (threadIdx.x >> 6);
    int lane = threadIdx.x & 63;
    if (n >= N_NODES) return;
    const unsigned short* fth = ft + (size_t)h * N_NODES * 128;
    size_t obase = (size_t)n * 1024 + h * 128;
    int start = indptr[n], end = indptr[n + 1];
    int q   = lane & 15;   // column group: elems 8q..8q+7
    int sub = lane >> 4;   // which of 4 edges this iteration

    if (end <= start) {
        if (lane < 16) { uint4 z = make_uint4(0,0,0,0); *(uint4*)(outp + obase + 8 * q) = z; }
        return;
    }
    float a1v = a1[n * 8 + h];

    // pass 1: segment max; cache chunk-0 logits
    int sidx0 = 0; float sv0 = 0.f;
    float m = -INFINITY;
    {
        int e = start + lane;
        if (e < end) {
            sidx0 = csr_src[e];
            sv0 = leaky(a1v + a2[sidx0 * 8 + h]);
            m = sv0;
        }
        for (int e2 = start + 64 + lane; e2 < end; e2 += 64)
            m = fmaxf(m, leaky(a1v + a2[csr_src[e2] * 8 + h]));
#pragma unroll
        for (int off = 32; off > 0; off >>= 1) m = fmaxf(m, __shfl_xor(m, off));
    }

    // pass 2: weights + quarter-wave 16B gather-accumulate
    float denom = 0.f;
    float4 accA = make_float4(0.f, 0.f, 0.f, 0.f);
    float4 accB = make_float4(0.f, 0.f, 0.f, 0.f);
    for (int base = start; base < end; base += 64) {
        int ee = base + lane;
        float wgt = 0.f;
        int sidx = sidx0;
        if (base == start) {
            if (ee < end) wgt = expf(sv0 - m);
        } else if (ee < end) {
            sidx = csr_src[ee];
            wgt = expf(leaky(a1v + a2[sidx * 8 + h]) - m);
        }
        denom += wgt;
        int cnt = min(64, end - base);
        for (int i = 0; i < cnt; i += 4) {
            int j  = i + sub;
            int jc = (j < cnt) ? j : i;
            float wj = __shfl(wgt, jc);
            int   sj = __shfl(sidx, jc);
            if (j >= cnt) wj = 0.f;
            uint4 v = *(const uint4*)(fth + (size_t)sj * 128 + 8 * q);
            accA.x += wj * bflo(v.x); accA.y += wj * bfhi(v.x);
            accA.z += wj * bflo(v.y); accA.w += wj * bfhi(v.y);
            accB.x += wj * bflo(v.z); accB.y += wj * bfhi(v.z);
            accB.z += wj * bflo(v.w); accB.w += wj * bfhi(v.w);
        }
    }
#pragma unroll
    for (int off = 32; off > 0; off >>= 1) denom += __shfl_xor(denom, off);
    // combine the 4 edge-subgroup partials (lanes differing in bits 4,5)
#pragma unroll
    for (int off = 16; off <= 32; off <<= 1) {
        accA.x += __shfl_xor(accA.x, off); accA.y += __shfl_xor(accA.y, off);
        accA.z += __shfl_xor(accA.z, off); accA.w += __shfl_xor(accA.w, off);
        accB.x += __shfl_xor(accB.x, off); accB.y += __shfl_xor(accB.y, off);
        accB.z += __shfl_xor(accB.z, off); accB.w += __shfl_xor(accB.w, off);
    }
    float inv = 1.f / denom;
    if (lane < 16) {
        float r[8] = {accA.x * inv, accA.y * inv, accA.z * inv, accA.w * inv,
                      accB.x * inv, accB.y * inv, accB.z * inv, accB.w * inv};
        unsigned pk[4];
#pragma unroll
        for (int u = 0; u < 4; ++u) {
            float e0 = (r[2*u]   > 0.f) ? r[2*u]   : expm1f(r[2*u]);
            float e1 = (r[2*u+1] > 0.f) ? r[2*u+1] : expm1f(r[2*u+1]);
            pk[u] = (unsigned)f2bf(e0) | ((unsigned)f2bf(e1) << 16);
        }
        *(uint4*)(outp + obase + 8 * q) = make_uint4(pk[0], pk[1], pk[2], pk[3]);
    }
}

// ---------------- final aggregate: H=1, Dh=64, bf16 in [N][64], fp32 out [N][64]
__global__ __launch_bounds__(256) void k_aggregate_final(
    const unsigned short* __restrict__ ft, const float* __restrict__ a1,
    const float* __restrict__ a2, const int* __restrict__ indptr,
    const int* __restrict__ csr_src, float* __restrict__ outp)
{
    int n = blockIdx.x * 4 + (threadIdx.x >> 6);
    int lane = threadIdx.x & 63;
    if (n >= N_NODES) return;
    size_t obase = (size_t)n * 64;
    int start = indptr[n], end = indptr[n + 1];

    if (end <= start) {
        if (lane < 32) *(float2*)(outp + obase + 2 * lane) = make_float2(0.f, 0.f);
        return;
    }
    float a1v = a1[n];

    int sidx0 = 0; float sv0 = 0.f;
    float m = -INFINITY;
    {
        int e = start + lane;
        if (e < end) {
            sidx0 = csr_src[e];
            sv0 = leaky(a1v + a2[sidx0]);
            m = sv0;
        }
        for (int e2 = start + 64 + lane; e2 < end; e2 += 64)
            m = fmaxf(m, leaky(a1v + a2[csr_src[e2]]));
#pragma unroll
        for (int off = 32; off > 0; off >>= 1) m = fmaxf(m, __shfl_xor(m, off));
    }

    float denom = 0.f, acc0 = 0.f, acc1 = 0.f;
    for (int base = start; base < end; base += 64) {
        int e = base + lane;
        float wgt = 0.f;
        int sidx = sidx0;
        if (base == start) {
            if (e < end) wgt = expf(sv0 - m);
        } else if (e < end) {
            sidx = csr_src[e];
            wgt = expf(leaky(a1v + a2[sidx]) - m);
        }
        denom += wgt;
        int cnt = min(64, end - base);
        int half = lane >> 5, idx = lane & 31;
        for (int i = 0; i < cnt; i += 2) {
            int j = i + half;
            float wj = (j < cnt) ? __shfl(wgt, j) : 0.f;
            int   sj = __shfl(sidx, (j < cnt) ? j : i);
            unsigned v = *(const unsigned*)(ft + (size_t)sj * 64 + 2 * idx);
            acc0 += wj * bflo(v);
            acc1 += wj * bfhi(v);
        }
    }
#pragma unroll
    for (int off = 32; off > 0; off >>= 1) denom += __shfl_xor(denom, off);
    float inv = 1.f / denom;

    acc0 += __shfl_xor(acc0, 32);
    acc1 += __shfl_xor(acc1, 32);
    float r0 = acc0 * inv, r1 = acc1 * inv;
    r0 = (r0 > 0.f) ? r0 : expm1f(r0);
    r1 = (r1 > 0.f) ? r1 : expm1f(r1);
    if (lane < 32)
        *(float2*)(outp + obase + 2 * lane) = make_float2(r0, r1);
}

// ---------------- launch ----------------
extern "C" void kernel_launch(void* const* d_in, const int* in_sizes, int n_in,
                              void* d_out, int out_size, void* d_ws, size_t ws_size,
                              hipStream_t stream) {
    const float* features = (const float*)d_in[0];
    const int*   src      = (const int*)d_in[1];
    const int*   dst      = (const int*)d_in[2];
    const float* W0  = (const float*)d_in[3];
    const float* b0  = (const float*)d_in[4];
    const float* al0 = (const float*)d_in[5];
    const float* alb0= (const float*)d_in[6];
    const float* ar0 = (const float*)d_in[7];
    const float* arb0= (const float*)d_in[8];
    const float* W1  = (const float*)d_in[9];
    const float* b1  = (const float*)d_in[10];
    const float* al1 = (const float*)d_in[11];
    const float* alb1= (const float*)d_in[12];
    const float* ar1 = (const float*)d_in[13];
    const float* arb1= (const float*)d_in[14];
    const float* Wf  = (const float*)d_in[15];
    const float* bff = (const float*)d_in[16];
    const float* alf = (const float*)d_in[17];
    const float* albf= (const float*)d_in[18];
    const float* arf = (const float*)d_in[19];
    const float* arbf= (const float*)d_in[20];
    float* out = (float*)d_out;

    // workspace carve
    char* wp = (char*)d_ws;
    unsigned short* ft16  = (unsigned short*)wp;  wp += (size_t)N_NODES * 1024 * 2;  // [8][N][128] (or [N][64] final)
    unsigned short* xb16  = (unsigned short*)wp;  wp += (size_t)N_NODES * 1024 * 2;  // [N][1024]
    unsigned short* feat16= (unsigned short*)wp;  wp += (size_t)N_NODES * 512 * 2;
    unsigned short* w0t   = (unsigned short*)wp;  wp += (size_t)N_HEADS * D_HID * D_IN * 2;
    unsigned short* w1t   = (unsigned short*)wp;  wp += (size_t)N_HEADS * D_HID * 1024 * 2;
    unsigned short* wft   = (unsigned short*)wp;  wp += (size_t)N_CLS * 1024 * 2;
    float* a1             = (float*)wp;           wp += (size_t)N_NODES * N_HEADS * 4;
    float* a2             = (float*)wp;           wp += (size_t)N_NODES * N_HEADS * 4;
    int* counts = (int*)wp;                       wp += (size_t)N_NODES * 4;
    int* indptr = (int*)wp;                       wp += (size_t)(N_NODES + 1) * 4;
    int* cursor = (int*)wp;                       wp += (size_t)N_NODES * 4;
    int* csr    = (int*)wp;

    // ---- CSR build
    k_zero<<<(N_NODES + 255) / 256, 256, 0, stream>>>(counts, N_NODES);
    k_count<<<(N_EDGES + 255) / 256, 256, 0, stream>>>(dst, counts, N_EDGES);
    k_scan<<<1, 1024, 0, stream>>>(counts, indptr, cursor, N_NODES);
    k_scatter<<<(N_EDGES + 255) / 256, 256, 0, stream>>>(src, dst, cursor, csr, N_EDGES);

    // ---- conversions
    k_cvtA<<<(N_NODES * D_IN / 4 + 255) / 256, 256, 0, stream>>>(features, feat16, N_NODES * D_IN / 4);
    k_cvtW<<<dim3(D_IN / 64, D_HID / 64, N_HEADS), 256, 0, stream>>>(W0, w0t, D_IN, D_HID);
    k_cvtW<<<dim3(1024 / 64, D_HID / 64, N_HEADS), 256, 0, stream>>>(W1, w1t, 1024, D_HID);
    k_cvtW<<<dim3(1024 / 64, N_CLS / 64, 1), 256, 0, stream>>>(Wf, wft, 1024, N_CLS);

    const int gm = (N_NODES + 127) / 128;           // 157
    int nodeBlocks = (N_NODES + 3) / 4;             // 5000
    int aggBlocksH = 8 * nodeBlocks;                // 40000: bid&7 = head

    const long slab = (long)N_NODES * D_HID;        // per-head ft slab (elems)

    // ---- layer 0: feat16 [N,512] -> ft16 [8][N][128]
    k_gemm_bf16<128><<<dim3(gm, 1, N_HEADS), 256, 0, stream>>>(
        feat16, w0t, b0, ft16, N_NODES, D_IN, D_HID, slab);
    k_alogit<<<nodeBlocks, 256, 0, stream>>>(ft16, al0, alb0, ar0, arb0, a1, a2, N_HEADS, D_HID);
    k_aggregate8<<<aggBlocksH, 256, 0, stream>>>(ft16, a1, a2, indptr, csr, xb16);

    // ---- layer 1: xb16 [N,1024] -> ft16 [8][N][128]
    k_gemm_bf16<128><<<dim3(gm, 1, N_HEADS), 256, 0, stream>>>(
        xb16, w1t, b1, ft16, N_NODES, 1024, D_HID, slab);
    k_alogit<<<nodeBlocks, 256, 0, stream>>>(ft16, al1, alb1, ar1, arb1, a1, a2, N_HEADS, D_HID);
    k_aggregate8<<<aggBlocksH, 256, 0, stream>>>(ft16, a1, a2, indptr, csr, xb16);

    // ---- final layer: xb16 [N,1024] -> ft16 [N,64] -> out [N,64]
    k_gemm_bf16<64><<<dim3(gm, 1, 1), 256, 0, stream>>>(
        xb16, wft, bff, ft16, N_NODES, 1024, N_CLS, 0);
    k_alogit<<<nodeBlocks, 256, 0, stream>>>(ft16, alf, albf, arf, arbf, a1, a2, 1, N_CLS);
    k_aggregate_final<<<nodeBlocks, 256, 0, stream>>>(ft16, a1, a2, indptr, csr, out);
}

// Round 6
// 646.332 us; speedup vs baseline: 1.0222x; 1.0222x over previous
//
#include <hip/hip_runtime.h>
#include <math.h>

// Problem constants (match reference)
#define N_NODES 20000
#define N_EDGES 320000
#define D_IN    512
#define D_HID   128
#define N_HEADS 8
#define N_CLS   64

typedef __bf16 bf16x8 __attribute__((ext_vector_type(8)));
typedef float  f32x4  __attribute__((ext_vector_type(4)));

__device__ __forceinline__ float leaky(float x) { return fmaxf(x, 0.01f * x); }

// fp32 -> bf16 round-to-nearest-even
__device__ __forceinline__ unsigned short f2bf(float f) {
    unsigned u = __float_as_uint(f);
    return (unsigned short)((u + 0x7FFFu + ((u >> 16) & 1u)) >> 16);
}
__device__ __forceinline__ float bflo(unsigned v) { return __uint_as_float(v << 16); }
__device__ __forceinline__ float bfhi(unsigned v) { return __uint_as_float(v & 0xffff0000u); }

__device__ __forceinline__ void gl_lds16(const void* g, void* l) {
    __builtin_amdgcn_global_load_lds((const __attribute__((address_space(1))) void*)g,
                                     (__attribute__((address_space(3))) void*)l, 16, 0, 0);
}

// ---------------- CSR build (rebuilt every call) ----------------
__global__ void k_zero(int* __restrict__ p, int n) {
    int i = blockIdx.x * blockDim.x + threadIdx.x;
    if (i < n) p[i] = 0;
}

__global__ void k_count(const int* __restrict__ dst, int* __restrict__ counts, int e) {
    int i = blockIdx.x * blockDim.x + threadIdx.x;
    if (i < e) atomicAdd(&counts[dst[i]], 1);
}

__global__ void k_scan(const int* __restrict__ counts, int* __restrict__ indptr,
                       int* __restrict__ cursor, int n) {
    __shared__ int sdata[1024];
    __shared__ int srun;
    int t = threadIdx.x;
    if (t == 0) srun = 0;
    __syncthreads();
    for (int base = 0; base < n; base += 1024) {
        int idx = base + t;
        int v = (idx < n) ? counts[idx] : 0;
        sdata[t] = v;
        __syncthreads();
        for (int off = 1; off < 1024; off <<= 1) {
            int x = (t >= off) ? sdata[t - off] : 0;
            __syncthreads();
            sdata[t] += x;
            __syncthreads();
        }
        int incl = sdata[t];
        int run = srun;
        if (idx < n) {
            indptr[idx] = run + incl - v;
            cursor[idx] = run + incl - v;
        }
        __syncthreads();
        if (t == 1023) srun = run + incl;
        __syncthreads();
    }
    if (t == 0) indptr[n] = srun;
}

__global__ void k_scatter(const int* __restrict__ src, const int* __restrict__ dst,
                          int* __restrict__ cursor, int* __restrict__ csr_src, int e) {
    int i = blockIdx.x * blockDim.x + threadIdx.x;
    if (i < e) {
        int pos = atomicAdd(&cursor[dst[i]], 1);
        csr_src[pos] = src[i];
    }
}

// ---------------- conversions ----------------
__global__ void k_cvtA(const float* __restrict__ in, unsigned short* __restrict__ out, int n4) {
    int i = blockIdx.x * blockDim.x + threadIdx.x;
    if (i < n4) {
        float4 v = ((const float4*)in)[i];
        unsigned long long pk =
            (unsigned long long)f2bf(v.x) | ((unsigned long long)f2bf(v.y) << 16) |
            ((unsigned long long)f2bf(v.z) << 32) | ((unsigned long long)f2bf(v.w) << 48);
        *(unsigned long long*)(out + (size_t)i * 4) = pk;
    }
}

// W [h][K][Nf] fp32 -> Wt [h][Nf][K] bf16
__global__ void k_cvtW(const float* __restrict__ W, unsigned short* __restrict__ Wt,
                       int K, int Nf) {
    __shared__ float t[64][65];
    int k0 = blockIdx.x * 64, n0 = blockIdx.y * 64, h = blockIdx.z;
    const float* Wh = W + (size_t)h * K * Nf;
    unsigned short* Wth = Wt + (size_t)h * K * Nf;
    int tx = threadIdx.x & 63, ty = threadIdx.x >> 6;
#pragma unroll
    for (int i = 0; i < 16; ++i) {
        int k = ty + i * 4;
        t[k][tx] = Wh[(size_t)(k0 + k) * Nf + n0 + tx];
    }
    __syncthreads();
#pragma unroll
    for (int i = 0; i < 16; ++i) {
        int n = ty + i * 4;
        Wth[(size_t)(n0 + n) * K + k0 + tx] = f2bf(t[tx][n]);
    }
}

// ---------------- fused bf16 MFMA GEMM (2 heads per z-block) + alogit epilogue ----
// BM=128, BN=256 (= 2 heads x 128), BK=64, 4 waves (wm in {0,1} rows, wn in {0,1} = head).
// Outputs: ft slab [h][N][128] bf16; a1/a2 [N][8] fp32 (from fp32 accumulators).
__global__ __launch_bounds__(256) void k_gemm_fused(
    const unsigned short* __restrict__ A, const unsigned short* __restrict__ Bt,
    const float* __restrict__ bias, const float* __restrict__ al,
    const float* __restrict__ alb, const float* __restrict__ ar,
    const float* __restrict__ arb, unsigned short* __restrict__ C,
    float* __restrict__ a1, float* __restrict__ a2, int M, int K)
{
    constexpr int BM = 128, BK = 64, BNP = 256;
    __shared__ unsigned short As[BM * BK];    // 16 KB
    __shared__ unsigned short Bs[BNP * BK];   // 32 KB

    const int tid  = threadIdx.x;
    const int lane = tid & 63;
    const int wid  = tid >> 6;
    const int wm   = wid >> 1;      // 0..1: row half
    const int wn   = wid & 1;       // 0..1: which head of the pair
    const int m0   = blockIdx.x * BM;
    const int h0   = blockIdx.z * 2;
    const int h    = h0 + wn;

    const unsigned short* Bth = Bt + (size_t)h0 * 128 * K;  // pair slab, rows 0..255
    const int rsub = lane & 15;
    const int rhi  = lane >> 4;
    const int wbase = tid & ~63;

    f32x4 acc[4][8];
#pragma unroll
    for (int i = 0; i < 4; ++i)
#pragma unroll
        for (int j = 0; j < 8; ++j) acc[i][j] = (f32x4){0.f, 0.f, 0.f, 0.f};

    for (int k0 = 0; k0 < K; k0 += BK) {
        // A: 128 rows x 64 bf16, 4 passes
#pragma unroll
        for (int p = 0; p < 4; ++p) {
            int o    = (p * 256 + tid) * 16;
            int row  = o >> 7;
            int icol = (o & 127) ^ ((row & 7) << 4);
            int grow = m0 + row; if (grow > M - 1) grow = M - 1;
            gl_lds16(A + (size_t)grow * K + k0 + (icol >> 1),
                     (void*)((char*)As + (p * 256 + wbase) * 16));
        }
        // B: 256 rows x 64 bf16, 8 passes
#pragma unroll
        for (int p = 0; p < 8; ++p) {
            int o    = (p * 256 + tid) * 16;
            int row  = o >> 7;
            int icol = (o & 127) ^ ((row & 7) << 4);
            gl_lds16(Bth + (size_t)row * K + k0 + (icol >> 1),
                     (void*)((char*)Bs + (p * 256 + wbase) * 16));
        }
        __syncthreads();

#pragma unroll
        for (int q = 0; q < 2; ++q) {
            bf16x8 av[4], bv[8];
#pragma unroll
            for (int mi = 0; mi < 4; ++mi) {
                int row  = wm * 64 + mi * 16 + rsub;
                int icol = (q * 64 + rhi * 16) ^ ((row & 7) << 4);
                av[mi] = *(const bf16x8*)((const char*)As + row * 128 + icol);
            }
#pragma unroll
            for (int ni = 0; ni < 8; ++ni) {
                int row  = wn * 128 + ni * 16 + rsub;
                int icol = (q * 64 + rhi * 16) ^ ((row & 7) << 4);
                bv[ni] = *(const bf16x8*)((const char*)Bs + row * 128 + icol);
            }
#pragma unroll
            for (int mi = 0; mi < 4; ++mi)
#pragma unroll
                for (int ni = 0; ni < 8; ++ni)
                    acc[mi][ni] = __builtin_amdgcn_mfma_f32_16x16x32_bf16(
                        av[mi], bv[ni], acc[mi][ni], 0, 0, 0);
        }
        __syncthreads();
    }

    // bias add into acc (a1/a2 must include bias: ft = xW + b)
#pragma unroll
    for (int ni = 0; ni < 8; ++ni) {
        float bvv = bias[h * 128 + ni * 16 + rsub];
#pragma unroll
        for (int mi = 0; mi < 4; ++mi)
#pragma unroll
            for (int r = 0; r < 4; ++r) acc[mi][ni][r] += bvv;
    }

    // store ft (bf16 slab [h][N][128]); C/D layout col=lane&15, row=(lane>>4)*4+reg
    unsigned short* Ch = C + (size_t)h * N_NODES * 128;
#pragma unroll
    for (int ni = 0; ni < 8; ++ni) {
        int col = ni * 16 + rsub;
#pragma unroll
        for (int mi = 0; mi < 4; ++mi) {
            int rowb = m0 + wm * 64 + mi * 16 + rhi * 4;
#pragma unroll
            for (int r = 0; r < 4; ++r) {
                int row = rowb + r;
                if (row < M) Ch[(size_t)row * 128 + col] = f2bf(acc[mi][ni][r]);
            }
        }
    }

    // fused attention logits: a1[row][h] = ft_row . al_h + alb_h (fp32 acc)
    float alv[8], arv[8];
#pragma unroll
    for (int ni = 0; ni < 8; ++ni) {
        alv[ni] = al[h * 128 + ni * 16 + rsub];
        arv[ni] = ar[h * 128 + ni * 16 + rsub];
    }
    float albv = alb[h], arbv = arb[h];
#pragma unroll
    for (int mi = 0; mi < 4; ++mi) {
#pragma unroll
        for (int r = 0; r < 4; ++r) {
            float s1 = 0.f, s2 = 0.f;
#pragma unroll
            for (int ni = 0; ni < 8; ++ni) {
                s1 += acc[mi][ni][r] * alv[ni];
                s2 += acc[mi][ni][r] * arv[ni];
            }
#pragma unroll
            for (int off = 1; off <= 8; off <<= 1) {
                s1 += __shfl_xor(s1, off);
                s2 += __shfl_xor(s2, off);
            }
            if (rsub == 0) {
                int row = m0 + wm * 64 + mi * 16 + rhi * 4 + r;
                if (row < M) {
                    a1[row * 8 + h] = s1 + albv;
                    a2[row * 8 + h] = s2 + arbv;
                }
            }
        }
    }
}

// ---------------- final-layer GEMM (BN=64, unfused) ----------------
template<int BN>
__global__ __launch_bounds__(256) void k_gemm_bf16(
    const unsigned short* __restrict__ A, const unsigned short* __restrict__ Bt,
    const float* __restrict__ bias, unsigned short* __restrict__ C,
    int M, int K, int ldc)
{
    constexpr int BM = 128, BK = 64;
    constexpr int WN    = 1;
    constexpr int MFRAG = 2;
    constexpr int NFRAG = 4;

    __shared__ unsigned short As[BM * BK];
    __shared__ unsigned short Bs[BN * BK];

    const int tid  = threadIdx.x;
    const int lane = tid & 63;
    const int wid  = tid >> 6;
    const int wm   = wid / WN;
    const int wn   = wid % WN;
    const int m0   = blockIdx.x * BM;

    const int rsub = lane & 15;
    const int rhi  = lane >> 4;
    const int wbase = tid & ~63;

    f32x4 acc[MFRAG][NFRAG];
#pragma unroll
    for (int i = 0; i < MFRAG; ++i)
#pragma unroll
        for (int j = 0; j < NFRAG; ++j) acc[i][j] = (f32x4){0.f, 0.f, 0.f, 0.f};

    for (int k0 = 0; k0 < K; k0 += BK) {
#pragma unroll
        for (int p = 0; p < 4; ++p) {
            int o    = (p * 256 + tid) * 16;
            int row  = o >> 7;
            int icol = (o & 127) ^ ((row & 7) << 4);
            int grow = m0 + row; if (grow > M - 1) grow = M - 1;
            gl_lds16(A + (size_t)grow * K + k0 + (icol >> 1),
                     (void*)((char*)As + (p * 256 + wbase) * 16));
        }
#pragma unroll
        for (int p = 0; p < BN / 32; ++p) {
            int o    = (p * 256 + tid) * 16;
            int row  = o >> 7;
            int icol = (o & 127) ^ ((row & 7) << 4);
            gl_lds16(Bt + (size_t)row * K + k0 + (icol >> 1),
                     (void*)((char*)Bs + (p * 256 + wbase) * 16));
        }
        __syncthreads();

        bf16x8 av[2][MFRAG], bv[2][NFRAG];
#pragma unroll
        for (int q = 0; q < 2; ++q) {
#pragma unroll
            for (int mi = 0; mi < MFRAG; ++mi) {
                int row  = wm * (MFRAG * 16) + mi * 16 + rsub;
                int icol = (q * 64 + rhi * 16) ^ ((row & 7) << 4);
                av[q][mi] = *(const bf16x8*)((const char*)As + row * 128 + icol);
            }
#pragma unroll
            for (int ni = 0; ni < NFRAG; ++ni) {
                int row  = wn * (NFRAG * 16) + ni * 16 + rsub;
                int icol = (q * 64 + rhi * 16) ^ ((row & 7) << 4);
                bv[q][ni] = *(const bf16x8*)((const char*)Bs + row * 128 + icol);
            }
        }
#pragma unroll
        for (int q = 0; q < 2; ++q)
#pragma unroll
            for (int mi = 0; mi < MFRAG; ++mi)
#pragma unroll
                for (int ni = 0; ni < NFRAG; ++ni)
                    acc[mi][ni] = __builtin_amdgcn_mfma_f32_16x16x32_bf16(
                        av[q][mi], bv[q][ni], acc[mi][ni], 0, 0, 0);
        __syncthreads();
    }

#pragma unroll
    for (int ni = 0; ni < NFRAG; ++ni) {
        int col  = wn * (NFRAG * 16) + ni * 16 + rsub;
        float bvv = bias[col];
#pragma unroll
        for (int mi = 0; mi < MFRAG; ++mi) {
            int rowb = m0 + wm * (MFRAG * 16) + mi * 16 + rhi * 4;
#pragma unroll
            for (int r = 0; r < 4; ++r) {
                int row = rowb + r;
                if (row < M) C[(size_t)row * ldc + col] = f2bf(acc[mi][ni][r] + bvv);
            }
        }
    }
}

// ---------------- per-node attention logits (final layer only) ----------------
__global__ __launch_bounds__(256) void k_alogit(
    const unsigned short* __restrict__ ft, const float* __restrict__ al,
    const float* __restrict__ alb, const float* __restrict__ ar,
    const float* __restrict__ arb, float* __restrict__ a1,
    float* __restrict__ a2, int H_, int Dh)
{
    int n = blockIdx.x * 4 + (threadIdx.x >> 6);
    int lane = threadIdx.x & 63;
    if (n >= N_NODES) return;
    for (int h = 0; h < H_; ++h) {
        size_t base = ((size_t)h * N_NODES + n) * Dh;
        float s1 = 0.f, s2 = 0.f;
        for (int j0 = 2 * lane; j0 < Dh; j0 += 128) {
            unsigned v = *(const unsigned*)(ft + base + j0);
            float lo = bflo(v), hi = bfhi(v);
            float2 A = *(const float2*)(al + h * Dh + j0);
            float2 R = *(const float2*)(ar + h * Dh + j0);
            s1 += lo * A.x + hi * A.y;
            s2 += lo * R.x + hi * R.y;
        }
#pragma unroll
        for (int off = 32; off > 0; off >>= 1) {
            s1 += __shfl_xor(s1, off);
            s2 += __shfl_xor(s2, off);
        }
        if (lane == 0) {
            a1[n * H_ + h] = s1 + alb[h];
            a2[n * H_ + h] = s2 + arb[h];
        }
    }
}

// ---------------- hidden-layer aggregate: H=8, Dh=128 ----------------
// head = blockIdx.x & 7 (XCD L2 affinity on [h][N][128] slabs).
// Quarter-wave 16B gathers, software-pipelined: 4 loads in flight (16 edges/iter),
// 2-load remainder. Tail slots clamp to edge cnt-1 (weight 0, dup row ~free).
__global__ __launch_bounds__(256) void k_aggregate8(
    const unsigned short* __restrict__ ft, const float* __restrict__ a1,
    const float* __restrict__ a2, const int* __restrict__ indptr,
    const int* __restrict__ csr_src, unsigned short* __restrict__ outp)
{
    int h = blockIdx.x & 7;
    int n = (blockIdx.x >> 3) * 4 + (threadIdx.x >> 6);
    int lane = threadIdx.x & 63;
    if (n >= N_NODES) return;
    const unsigned short* fth = ft + (size_t)h * N_NODES * 128;
    size_t obase = (size_t)n * 1024 + h * 128;
    int start = indptr[n], end = indptr[n + 1];
    int q   = lane & 15;
    int sub = lane >> 4;

    if (end <= start) {
        if (lane < 16) { uint4 z = make_uint4(0, 0, 0, 0); *(uint4*)(outp + obase + 8 * q) = z; }
        return;
    }
    float a1v = a1[n * 8 + h];

    // pass 1: segment max; cache chunk-0 logits
    int sidx0 = 0; float sv0 = 0.f;
    float m = -INFINITY;
    {
        int e = start + lane;
        if (e < end) {
            sidx0 = csr_src[e];
            sv0 = leaky(a1v + a2[sidx0 * 8 + h]);
            m = sv0;
        }
        for (int e2 = start + 64 + lane; e2 < end; e2 += 64)
            m = fmaxf(m, leaky(a1v + a2[csr_src[e2] * 8 + h]));
#pragma unroll
        for (int off = 32; off > 0; off >>= 1) m = fmaxf(m, __shfl_xor(m, off));
    }

    // pass 2: weights + pipelined quarter-wave gather-accumulate
    float denom = 0.f;
    float4 accA = make_float4(0.f, 0.f, 0.f, 0.f);
    float4 accB = make_float4(0.f, 0.f, 0.f, 0.f);
    for (int base = start; base < end; base += 64) {
        int ee = base + lane;
        float wgt = 0.f;
        int sidx = sidx0;
        if (base == start) {
            if (ee < end) wgt = expf(sv0 - m);
        } else if (ee < end) {
            sidx = csr_src[ee];
            wgt = expf(leaky(a1v + a2[sidx * 8 + h]) - m);
        }
        denom += wgt;
        int cnt = min(64, end - base);

        auto iss = [&](int i, float& W, int& S, uint4& V) {
            int j  = i + sub;
            int jc = (j < cnt) ? j : (cnt - 1);
            W = __shfl(wgt, jc);
            S = __shfl(sidx, jc);
            if (j >= cnt) W = 0.f;
            V = *(const uint4*)(fth + (size_t)S * 128 + 8 * q);
        };
        auto accf = [&](const uint4& V, float W) {
            accA.x += W * bflo(V.x); accA.y += W * bfhi(V.x);
            accA.z += W * bflo(V.y); accA.w += W * bfhi(V.y);
            accB.x += W * bflo(V.z); accB.y += W * bfhi(V.z);
            accB.z += W * bflo(V.w); accB.w += W * bfhi(V.w);
        };

        int i = 0;
        for (; i + 16 <= cnt; i += 16) {
            float w0, w1, w2, w3; int s0, s1, s2, s3; uint4 v0, v1, v2, v3;
            iss(i, w0, s0, v0); iss(i + 4, w1, s1, v1);
            iss(i + 8, w2, s2, v2); iss(i + 12, w3, s3, v3);
            accf(v0, w0); accf(v1, w1); accf(v2, w2); accf(v3, w3);
        }
        for (; i < cnt; i += 8) {
            float w0, w1; int s0, s1; uint4 v0, v1;
            iss(i, w0, s0, v0); iss(i + 4, w1, s1, v1);
            accf(v0, w0); accf(v1, w1);
        }
    }
#pragma unroll
    for (int off = 32; off > 0; off >>= 1) denom += __shfl_xor(denom, off);
    // combine the 4 edge-subgroup partials (lanes differing in bits 4,5)
#pragma unroll
    for (int off = 16; off <= 32; off <<= 1) {
        accA.x += __shfl_xor(accA.x, off); accA.y += __shfl_xor(accA.y, off);
        accA.z += __shfl_xor(accA.z, off); accA.w += __shfl_xor(accA.w, off);
        accB.x += __shfl_xor(accB.x, off); accB.y += __shfl_xor(accB.y, off);
        accB.z += __shfl_xor(accB.z, off); accB.w += __shfl_xor(accB.w, off);
    }
    float inv = 1.f / denom;
    if (lane < 16) {
        float r[8] = {accA.x * inv, accA.y * inv, accA.z * inv, accA.w * inv,
                      accB.x * inv, accB.y * inv, accB.z * inv, accB.w * inv};
        unsigned pk[4];
#pragma unroll
        for (int u = 0; u < 4; ++u) {
            float e0 = (r[2*u]   > 0.f) ? r[2*u]   : expm1f(r[2*u]);
            float e1 = (r[2*u+1] > 0.f) ? r[2*u+1] : expm1f(r[2*u+1]);
            pk[u] = (unsigned)f2bf(e0) | ((unsigned)f2bf(e1) << 16);
        }
        *(uint4*)(outp + obase + 8 * q) = make_uint4(pk[0], pk[1], pk[2], pk[3]);
    }
}

// ---------------- final aggregate: H=1, Dh=64, bf16 in [N][64], fp32 out ----------------
__global__ __launch_bounds__(256) void k_aggregate_final(
    const unsigned short* __restrict__ ft, const float* __restrict__ a1,
    const float* __restrict__ a2, const int* __restrict__ indptr,
    const int* __restrict__ csr_src, float* __restrict__ outp)
{
    int n = blockIdx.x * 4 + (threadIdx.x >> 6);
    int lane = threadIdx.x & 63;
    if (n >= N_NODES) return;
    size_t obase = (size_t)n * 64;
    int start = indptr[n], end = indptr[n + 1];

    if (end <= start) {
        if (lane < 32) *(float2*)(outp + obase + 2 * lane) = make_float2(0.f, 0.f);
        return;
    }
    float a1v = a1[n];

    int sidx0 = 0; float sv0 = 0.f;
    float m = -INFINITY;
    {
        int e = start + lane;
        if (e < end) {
            sidx0 = csr_src[e];
            sv0 = leaky(a1v + a2[sidx0]);
            m = sv0;
        }
        for (int e2 = start + 64 + lane; e2 < end; e2 += 64)
            m = fmaxf(m, leaky(a1v + a2[csr_src[e2]]));
#pragma unroll
        for (int off = 32; off > 0; off >>= 1) m = fmaxf(m, __shfl_xor(m, off));
    }

    float denom = 0.f, acc0 = 0.f, acc1 = 0.f;
    int half = lane >> 5, idx = lane & 31;
    for (int base = start; base < end; base += 64) {
        int e = base + lane;
        float wgt = 0.f;
        int sidx = sidx0;
        if (base == start) {
            if (e < end) wgt = expf(sv0 - m);
        } else if (e < end) {
            sidx = csr_src[e];
            wgt = expf(leaky(a1v + a2[sidx]) - m);
        }
        denom += wgt;
        int cnt = min(64, end - base);
        // 2 loads in flight: edges (i,i+1) and (i+2,i+3) per iteration
        for (int i = 0; i < cnt; i += 4) {
            int j0 = i + half, j1 = i + 2 + half;
            int jc0 = (j0 < cnt) ? j0 : (cnt - 1);
            int jc1 = (j1 < cnt) ? j1 : (cnt - 1);
            float w0 = __shfl(wgt, jc0); int s0 = __shfl(sidx, jc0);
            float w1 = __shfl(wgt, jc1); int s1 = __shfl(sidx, jc1);
            if (j0 >= cnt) w0 = 0.f;
            if (j1 >= cnt) w1 = 0.f;
            unsigned v0 = *(const unsigned*)(ft + (size_t)s0 * 64 + 2 * idx);
            unsigned v1 = *(const unsigned*)(ft + (size_t)s1 * 64 + 2 * idx);
            acc0 += w0 * bflo(v0) + w1 * bflo(v1);
            acc1 += w0 * bfhi(v0) + w1 * bfhi(v1);
        }
    }
#pragma unroll
    for (int off = 32; off > 0; off >>= 1) denom += __shfl_xor(denom, off);
    float inv = 1.f / denom;

    acc0 += __shfl_xor(acc0, 32);
    acc1 += __shfl_xor(acc1, 32);
    float r0 = acc0 * inv, r1 = acc1 * inv;
    r0 = (r0 > 0.f) ? r0 : expm1f(r0);
    r1 = (r1 > 0.f) ? r1 : expm1f(r1);
    if (lane < 32)
        *(float2*)(outp + obase + 2 * lane) = make_float2(r0, r1);
}

// ---------------- launch ----------------
extern "C" void kernel_launch(void* const* d_in, const int* in_sizes, int n_in,
                              void* d_out, int out_size, void* d_ws, size_t ws_size,
                              hipStream_t stream) {
    const float* features = (const float*)d_in[0];
    const int*   src      = (const int*)d_in[1];
    const int*   dst      = (const int*)d_in[2];
    const float* W0  = (const float*)d_in[3];
    const float* b0  = (const float*)d_in[4];
    const float* al0 = (const float*)d_in[5];
    const float* alb0= (const float*)d_in[6];
    const float* ar0 = (const float*)d_in[7];
    const float* arb0= (const float*)d_in[8];
    const float* W1  = (const float*)d_in[9];
    const float* b1  = (const float*)d_in[10];
    const float* al1 = (const float*)d_in[11];
    const float* alb1= (const float*)d_in[12];
    const float* ar1 = (const float*)d_in[13];
    const float* arb1= (const float*)d_in[14];
    const float* Wf  = (const float*)d_in[15];
    const float* bff = (const float*)d_in[16];
    const float* alf = (const float*)d_in[17];
    const float* albf= (const float*)d_in[18];
    const float* arf = (const float*)d_in[19];
    const float* arbf= (const float*)d_in[20];
    float* out = (float*)d_out;

    // workspace carve
    char* wp = (char*)d_ws;
    unsigned short* ft16  = (unsigned short*)wp;  wp += (size_t)N_NODES * 1024 * 2;  // [8][N][128] (or [N][64] final)
    unsigned short* xb16  = (unsigned short*)wp;  wp += (size_t)N_NODES * 1024 * 2;  // [N][1024]
    unsigned short* feat16= (unsigned short*)wp;  wp += (size_t)N_NODES * 512 * 2;
    unsigned short* w0t   = (unsigned short*)wp;  wp += (size_t)N_HEADS * D_HID * D_IN * 2;
    unsigned short* w1t   = (unsigned short*)wp;  wp += (size_t)N_HEADS * D_HID * 1024 * 2;
    unsigned short* wft   = (unsigned short*)wp;  wp += (size_t)N_CLS * 1024 * 2;
    float* a1             = (float*)wp;           wp += (size_t)N_NODES * N_HEADS * 4;
    float* a2             = (float*)wp;           wp += (size_t)N_NODES * N_HEADS * 4;
    int* counts = (int*)wp;                       wp += (size_t)N_NODES * 4;
    int* indptr = (int*)wp;                       wp += (size_t)(N_NODES + 1) * 4;
    int* cursor = (int*)wp;                       wp += (size_t)N_NODES * 4;
    int* csr    = (int*)wp;

    // ---- CSR build
    k_zero<<<(N_NODES + 255) / 256, 256, 0, stream>>>(counts, N_NODES);
    k_count<<<(N_EDGES + 255) / 256, 256, 0, stream>>>(dst, counts, N_EDGES);
    k_scan<<<1, 1024, 0, stream>>>(counts, indptr, cursor, N_NODES);
    k_scatter<<<(N_EDGES + 255) / 256, 256, 0, stream>>>(src, dst, cursor, csr, N_EDGES);

    // ---- conversions
    k_cvtA<<<(N_NODES * D_IN / 4 + 255) / 256, 256, 0, stream>>>(features, feat16, N_NODES * D_IN / 4);
    k_cvtW<<<dim3(D_IN / 64, D_HID / 64, N_HEADS), 256, 0, stream>>>(W0, w0t, D_IN, D_HID);
    k_cvtW<<<dim3(1024 / 64, D_HID / 64, N_HEADS), 256, 0, stream>>>(W1, w1t, 1024, D_HID);
    k_cvtW<<<dim3(1024 / 64, N_CLS / 64, 1), 256, 0, stream>>>(Wf, wft, 1024, N_CLS);

    const int gm = (N_NODES + 127) / 128;           // 157
    int nodeBlocks = (N_NODES + 3) / 4;             // 5000
    int aggBlocksH = 8 * nodeBlocks;                // 40000: bid&7 = head

    // ---- layer 0: feat16 [N,512] -> ft16 [8][N][128] + a1/a2 (fused)
    k_gemm_fused<<<dim3(gm, 1, N_HEADS / 2), 256, 0, stream>>>(
        feat16, w0t, b0, al0, alb0, ar0, arb0, ft16, a1, a2, N_NODES, D_IN);
    k_aggregate8<<<aggBlocksH, 256, 0, stream>>>(ft16, a1, a2, indptr, csr, xb16);

    // ---- layer 1: xb16 [N,1024] -> ft16 [8][N][128] + a1/a2 (fused)
    k_gemm_fused<<<dim3(gm, 1, N_HEADS / 2), 256, 0, stream>>>(
        xb16, w1t, b1, al1, alb1, ar1, arb1, ft16, a1, a2, N_NODES, 1024);
    k_aggregate8<<<aggBlocksH, 256, 0, stream>>>(ft16, a1, a2, indptr, csr, xb16);

    // ---- final layer: xb16 [N,1024] -> ft16 [N,64] -> out [N,64]
    k_gemm_bf16<64><<<dim3(gm, 1, 1), 256, 0, stream>>>(
        xb16, wft, bff, ft16, N_NODES, 1024, N_CLS);
    k_alogit<<<nodeBlocks, 256, 0, stream>>>(ft16, alf, albf, arf, arbf, a1, a2, 1, N_CLS);
    k_aggregate_final<<<nodeBlocks, 256, 0, stream>>>(ft16, a1, a2, indptr, csr, out);
}

// Round 8
// 616.689 us; speedup vs baseline: 1.0713x; 1.0481x over previous
//
#include <hip/hip_runtime.h>
#include <math.h>

// Problem constants (match reference)
#define N_NODES 20000
#define N_EDGES 320000
#define D_IN    512
#define D_HID   128
#define N_HEADS 8
#define N_CLS   64

typedef __bf16 bf16x8 __attribute__((ext_vector_type(8)));
typedef float  f32x4  __attribute__((ext_vector_type(4)));

__device__ __forceinline__ float leaky(float x) { return fmaxf(x, 0.01f * x); }

// fp32 -> bf16 round-to-nearest-even
__device__ __forceinline__ unsigned short f2bf(float f) {
    unsigned u = __float_as_uint(f);
    return (unsigned short)((u + 0x7FFFu + ((u >> 16) & 1u)) >> 16);
}
__device__ __forceinline__ float bflo(unsigned v) { return __uint_as_float(v << 16); }
__device__ __forceinline__ float bfhi(unsigned v) { return __uint_as_float(v & 0xffff0000u); }

__device__ __forceinline__ void gl_lds16(const void* g, void* l) {
    __builtin_amdgcn_global_load_lds((const __attribute__((address_space(1))) void*)g,
                                     (__attribute__((address_space(3))) void*)l, 16, 0, 0);
}

// ---------------- CSR build (rebuilt every call) ----------------
__global__ void k_zero(int* __restrict__ p, int n) {
    int i = blockIdx.x * blockDim.x + threadIdx.x;
    if (i < n) p[i] = 0;
}

__global__ void k_count(const int* __restrict__ dst, int* __restrict__ counts, int e) {
    int i = blockIdx.x * blockDim.x + threadIdx.x;
    if (i < e) atomicAdd(&counts[dst[i]], 1);
}

__global__ void k_scan(const int* __restrict__ counts, int* __restrict__ indptr,
                       int* __restrict__ cursor, int n) {
    __shared__ int sdata[1024];
    __shared__ int srun;
    int t = threadIdx.x;
    if (t == 0) srun = 0;
    __syncthreads();
    for (int base = 0; base < n; base += 1024) {
        int idx = base + t;
        int v = (idx < n) ? counts[idx] : 0;
        sdata[t] = v;
        __syncthreads();
        for (int off = 1; off < 1024; off <<= 1) {
            int x = (t >= off) ? sdata[t - off] : 0;
            __syncthreads();
            sdata[t] += x;
            __syncthreads();
        }
        int incl = sdata[t];
        int run = srun;
        if (idx < n) {
            indptr[idx] = run + incl - v;
            cursor[idx] = run + incl - v;
        }
        __syncthreads();
        if (t == 1023) srun = run + incl;
        __syncthreads();
    }
    if (t == 0) indptr[n] = srun;
}

__global__ void k_scatter(const int* __restrict__ src, const int* __restrict__ dst,
                          int* __restrict__ cursor, int* __restrict__ csr_src, int e) {
    int i = blockIdx.x * blockDim.x + threadIdx.x;
    if (i < e) {
        int pos = atomicAdd(&cursor[dst[i]], 1);
        csr_src[pos] = src[i];
    }
}

// ---------------- conversions ----------------
__global__ void k_cvtA(const float* __restrict__ in, unsigned short* __restrict__ out, int n4) {
    int i = blockIdx.x * blockDim.x + threadIdx.x;
    if (i < n4) {
        float4 v = ((const float4*)in)[i];
        unsigned long long pk =
            (unsigned long long)f2bf(v.x) | ((unsigned long long)f2bf(v.y) << 16) |
            ((unsigned long long)f2bf(v.z) << 32) | ((unsigned long long)f2bf(v.w) << 48);
        *(unsigned long long*)(out + (size_t)i * 4) = pk;
    }
}

// W [h][K][Nf] fp32 -> Wt [h][Nf][K] bf16
__global__ void k_cvtW(const float* __restrict__ W, unsigned short* __restrict__ Wt,
                       int K, int Nf) {
    __shared__ float t[64][65];
    int k0 = blockIdx.x * 64, n0 = blockIdx.y * 64, h = blockIdx.z;
    const float* Wh = W + (size_t)h * K * Nf;
    unsigned short* Wth = Wt + (size_t)h * K * Nf;
    int tx = threadIdx.x & 63, ty = threadIdx.x >> 6;
#pragma unroll
    for (int i = 0; i < 16; ++i) {
        int k = ty + i * 4;
        t[k][tx] = Wh[(size_t)(k0 + k) * Nf + n0 + tx];
    }
    __syncthreads();
#pragma unroll
    for (int i = 0; i < 16; ++i) {
        int n = ty + i * 4;
        Wth[(size_t)(n0 + n) * K + k0 + tx] = f2bf(t[tx][n]);
    }
}

// ---------------- fused bf16 MFMA GEMM (2 heads per z-block) + alogit epilogue ----
// BM=128, BN=256 (= 2 heads x 128), BK=64, 4 waves (wm in {0,1} rows, wn in {0,1} = head).
// Outputs: ft [N][1024] bf16 (head h at cols h*128..); a1/a2 [N][8] fp32.
__global__ __launch_bounds__(256) void k_gemm_fused(
    const unsigned short* __restrict__ A, const unsigned short* __restrict__ Bt,
    const float* __restrict__ bias, const float* __restrict__ al,
    const float* __restrict__ alb, const float* __restrict__ ar,
    const float* __restrict__ arb, unsigned short* __restrict__ C,
    float* __restrict__ a1, float* __restrict__ a2, int M, int K)
{
    constexpr int BM = 128, BK = 64, BNP = 256;
    __shared__ unsigned short As[BM * BK];    // 16 KB
    __shared__ unsigned short Bs[BNP * BK];   // 32 KB

    const int tid  = threadIdx.x;
    const int lane = tid & 63;
    const int wid  = tid >> 6;
    const int wm   = wid >> 1;      // 0..1: row half
    const int wn   = wid & 1;       // 0..1: which head of the pair
    const int m0   = blockIdx.x * BM;
    const int h0   = blockIdx.z * 2;
    const int h    = h0 + wn;

    const unsigned short* Bth = Bt + (size_t)h0 * 128 * K;  // pair slab, rows 0..255
    const int rsub = lane & 15;
    const int rhi  = lane >> 4;
    const int wbase = tid & ~63;

    f32x4 acc[4][8];
#pragma unroll
    for (int i = 0; i < 4; ++i)
#pragma unroll
        for (int j = 0; j < 8; ++j) acc[i][j] = (f32x4){0.f, 0.f, 0.f, 0.f};

    for (int k0 = 0; k0 < K; k0 += BK) {
        // A: 128 rows x 64 bf16, 4 passes
#pragma unroll
        for (int p = 0; p < 4; ++p) {
            int o    = (p * 256 + tid) * 16;
            int row  = o >> 7;
            int icol = (o & 127) ^ ((row & 7) << 4);
            int grow = m0 + row; if (grow > M - 1) grow = M - 1;
            gl_lds16(A + (size_t)grow * K + k0 + (icol >> 1),
                     (void*)((char*)As + (p * 256 + wbase) * 16));
        }
        // B: 256 rows x 64 bf16, 8 passes
#pragma unroll
        for (int p = 0; p < 8; ++p) {
            int o    = (p * 256 + tid) * 16;
            int row  = o >> 7;
            int icol = (o & 127) ^ ((row & 7) << 4);
            gl_lds16(Bth + (size_t)row * K + k0 + (icol >> 1),
                     (void*)((char*)Bs + (p * 256 + wbase) * 16));
        }
        __syncthreads();

#pragma unroll
        for (int q = 0; q < 2; ++q) {
            bf16x8 av[4], bv[8];
#pragma unroll
            for (int mi = 0; mi < 4; ++mi) {
                int row  = wm * 64 + mi * 16 + rsub;
                int icol = (q * 64 + rhi * 16) ^ ((row & 7) << 4);
                av[mi] = *(const bf16x8*)((const char*)As + row * 128 + icol);
            }
#pragma unroll
            for (int ni = 0; ni < 8; ++ni) {
                int row  = wn * 128 + ni * 16 + rsub;
                int icol = (q * 64 + rhi * 16) ^ ((row & 7) << 4);
                bv[ni] = *(const bf16x8*)((const char*)Bs + row * 128 + icol);
            }
#pragma unroll
            for (int mi = 0; mi < 4; ++mi)
#pragma unroll
                for (int ni = 0; ni < 8; ++ni)
                    acc[mi][ni] = __builtin_amdgcn_mfma_f32_16x16x32_bf16(
                        av[mi], bv[ni], acc[mi][ni], 0, 0, 0);
        }
        __syncthreads();
    }

    // bias add into acc (a1/a2 must include bias: ft = xW + b)
#pragma unroll
    for (int ni = 0; ni < 8; ++ni) {
        float bvv = bias[h * 128 + ni * 16 + rsub];
#pragma unroll
        for (int mi = 0; mi < 4; ++mi)
#pragma unroll
            for (int r = 0; r < 4; ++r) acc[mi][ni][r] += bvv;
    }

    // store ft [N][1024]; C/D layout col=lane&15, row=(lane>>4)*4+reg
#pragma unroll
    for (int ni = 0; ni < 8; ++ni) {
        int col = h * 128 + ni * 16 + rsub;
#pragma unroll
        for (int mi = 0; mi < 4; ++mi) {
            int rowb = m0 + wm * 64 + mi * 16 + rhi * 4;
#pragma unroll
            for (int r = 0; r < 4; ++r) {
                int row = rowb + r;
                if (row < M) C[(size_t)row * 1024 + col] = f2bf(acc[mi][ni][r]);
            }
        }
    }

    // fused attention logits: a1[row][h] = ft_row . al_h + alb_h (fp32 acc)
    float alv[8], arv[8];
#pragma unroll
    for (int ni = 0; ni < 8; ++ni) {
        alv[ni] = al[h * 128 + ni * 16 + rsub];
        arv[ni] = ar[h * 128 + ni * 16 + rsub];
    }
    float albv = alb[h], arbv = arb[h];
#pragma unroll
    for (int mi = 0; mi < 4; ++mi) {
#pragma unroll
        for (int r = 0; r < 4; ++r) {
            float s1 = 0.f, s2 = 0.f;
#pragma unroll
            for (int ni = 0; ni < 8; ++ni) {
                s1 += acc[mi][ni][r] * alv[ni];
                s2 += acc[mi][ni][r] * arv[ni];
            }
#pragma unroll
            for (int off = 1; off <= 8; off <<= 1) {
                s1 += __shfl_xor(s1, off);
                s2 += __shfl_xor(s2, off);
            }
            if (rsub == 0) {
                int row = m0 + wm * 64 + mi * 16 + rhi * 4 + r;
                if (row < M) {
                    a1[row * 8 + h] = s1 + albv;
                    a2[row * 8 + h] = s2 + arbv;
                }
            }
        }
    }
}

// ---------------- final-layer GEMM (BN=64, unfused) ----------------
template<int BN>
__global__ __launch_bounds__(256) void k_gemm_bf16(
    const unsigned short* __restrict__ A, const unsigned short* __restrict__ Bt,
    const float* __restrict__ bias, unsigned short* __restrict__ C,
    int M, int K, int ldc)
{
    constexpr int BM = 128, BK = 64;
    constexpr int WN    = 1;
    constexpr int MFRAG = 2;
    constexpr int NFRAG = 4;

    __shared__ unsigned short As[BM * BK];
    __shared__ unsigned short Bs[BN * BK];

    const int tid  = threadIdx.x;
    const int lane = tid & 63;
    const int wid  = tid >> 6;
    const int wm   = wid / WN;
    const int wn   = wid % WN;
    const int m0   = blockIdx.x * BM;

    const int rsub = lane & 15;
    const int rhi  = lane >> 4;
    const int wbase = tid & ~63;

    f32x4 acc[MFRAG][NFRAG];
#pragma unroll
    for (int i = 0; i < MFRAG; ++i)
#pragma unroll
        for (int j = 0; j < NFRAG; ++j) acc[i][j] = (f32x4){0.f, 0.f, 0.f, 0.f};

    for (int k0 = 0; k0 < K; k0 += BK) {
#pragma unroll
        for (int p = 0; p < 4; ++p) {
            int o    = (p * 256 + tid) * 16;
            int row  = o >> 7;
            int icol = (o & 127) ^ ((row & 7) << 4);
            int grow = m0 + row; if (grow > M - 1) grow = M - 1;
            gl_lds16(A + (size_t)grow * K + k0 + (icol >> 1),
                     (void*)((char*)As + (p * 256 + wbase) * 16));
        }
#pragma unroll
        for (int p = 0; p < BN / 32; ++p) {
            int o    = (p * 256 + tid) * 16;
            int row  = o >> 7;
            int icol = (o & 127) ^ ((row & 7) << 4);
            gl_lds16(Bt + (size_t)row * K + k0 + (icol >> 1),
                     (void*)((char*)Bs + (p * 256 + wbase) * 16));
        }
        __syncthreads();

        bf16x8 av[2][MFRAG], bv[2][NFRAG];
#pragma unroll
        for (int q = 0; q < 2; ++q) {
#pragma unroll
            for (int mi = 0; mi < MFRAG; ++mi) {
                int row  = wm * (MFRAG * 16) + mi * 16 + rsub;
                int icol = (q * 64 + rhi * 16) ^ ((row & 7) << 4);
                av[q][mi] = *(const bf16x8*)((const char*)As + row * 128 + icol);
            }
#pragma unroll
            for (int ni = 0; ni < NFRAG; ++ni) {
                int row  = wn * (NFRAG * 16) + ni * 16 + rsub;
                int icol = (q * 64 + rhi * 16) ^ ((row & 7) << 4);
                bv[q][ni] = *(const bf16x8*)((const char*)Bs + row * 128 + icol);
            }
        }
#pragma unroll
        for (int q = 0; q < 2; ++q)
#pragma unroll
            for (int mi = 0; mi < MFRAG; ++mi)
#pragma unroll
                for (int ni = 0; ni < NFRAG; ++ni)
                    acc[mi][ni] = __builtin_amdgcn_mfma_f32_16x16x32_bf16(
                        av[q][mi], bv[q][ni], acc[mi][ni], 0, 0, 0);
        __syncthreads();
    }

#pragma unroll
    for (int ni = 0; ni < NFRAG; ++ni) {
        int col  = wn * (NFRAG * 16) + ni * 16 + rsub;
        float bvv = bias[col];
#pragma unroll
        for (int mi = 0; mi < MFRAG; ++mi) {
            int rowb = m0 + wm * (MFRAG * 16) + mi * 16 + rhi * 4;
#pragma unroll
            for (int r = 0; r < 4; ++r) {
                int row = rowb + r;
                if (row < M) C[(size_t)row * ldc + col] = f2bf(acc[mi][ni][r] + bvv);
            }
        }
    }
}

// ---------------- per-node attention logits (final layer only) ----------------
__global__ __launch_bounds__(256) void k_alogit(
    const unsigned short* __restrict__ ft, const float* __restrict__ al,
    const float* __restrict__ alb, const float* __restrict__ ar,
    const float* __restrict__ arb, float* __restrict__ a1,
    float* __restrict__ a2, int H_, int Dh)
{
    int n = blockIdx.x * 4 + (threadIdx.x >> 6);
    int lane = threadIdx.x & 63;
    if (n >= N_NODES) return;
    for (int h = 0; h < H_; ++h) {
        size_t base = ((size_t)h * N_NODES + n) * Dh;
        float s1 = 0.f, s2 = 0.f;
        for (int j0 = 2 * lane; j0 < Dh; j0 += 128) {
            unsigned v = *(const unsigned*)(ft + base + j0);
            float lo = bflo(v), hi = bfhi(v);
            float2 A = *(const float2*)(al + h * Dh + j0);
            float2 R = *(const float2*)(ar + h * Dh + j0);
            s1 += lo * A.x + hi * A.y;
            s2 += lo * R.x + hi * R.y;
        }
#pragma unroll
        for (int off = 32; off > 0; off >>= 1) {
            s1 += __shfl_xor(s1, off);
            s2 += __shfl_xor(s2, off);
        }
        if (lane == 0) {
            a1[n * H_ + h] = s1 + alb[h];
            a2[n * H_ + h] = s2 + arb[h];
        }
    }
}

// ---------------- all-heads aggregate: one wave per dst node ----------------
// ft [N][1024] bf16; per edge: 2 coalesced 1KB wave-loads + one 32B a2 load.
// Weights for all 8 heads staged per-chunk in a per-wave LDS table.
// Lane l owns elems [8l,8l+8) (head l/16) and [512+8l,512+8l+8) (head 4+l/16).
__global__ __launch_bounds__(256) void k_aggregate_ah(
    const unsigned short* __restrict__ ft, const float* __restrict__ a1,
    const float* __restrict__ a2, const int* __restrict__ indptr,
    const int* __restrict__ csr_src, unsigned short* __restrict__ outp)
{
    __shared__ float wtab[2][4][64][8];   // 16 KB: [parity][wave][edge][head]
    __shared__ int   stab[2][4][64];      // 2 KB

    const int wid  = threadIdx.x >> 6;
    const int lane = threadIdx.x & 63;
    int n = blockIdx.x * 4 + wid;
    if (n >= N_NODES) return;
    int start = indptr[n], end = indptr[n + 1];
    unsigned short* op = outp + (size_t)n * 1024;

    if (end <= start) {
        uint4 z = make_uint4(0, 0, 0, 0);
        *(uint4*)(op + lane * 8) = z;
        *(uint4*)(op + 512 + lane * 8) = z;
        return;
    }

    float a1v[8];
    *(float4*)&a1v[0] = *(const float4*)(a1 + n * 8);
    *(float4*)&a1v[4] = *(const float4*)(a1 + n * 8 + 4);

    // ---- pass 1: per-head segment max; cache chunk-0 logits
    float m[8], sv0[8];
    int sidx0 = 0;
#pragma unroll
    for (int h = 0; h < 8; ++h) { m[h] = -INFINITY; sv0[h] = -INFINITY; }
    {
        int e = start + lane;
        if (e < end) {
            sidx0 = csr_src[e];
            float4 x0 = *(const float4*)(a2 + (size_t)sidx0 * 8);
            float4 x1 = *(const float4*)(a2 + (size_t)sidx0 * 8 + 4);
            sv0[0] = leaky(a1v[0] + x0.x); sv0[1] = leaky(a1v[1] + x0.y);
            sv0[2] = leaky(a1v[2] + x0.z); sv0[3] = leaky(a1v[3] + x0.w);
            sv0[4] = leaky(a1v[4] + x1.x); sv0[5] = leaky(a1v[5] + x1.y);
            sv0[6] = leaky(a1v[6] + x1.z); sv0[7] = leaky(a1v[7] + x1.w);
#pragma unroll
            for (int h = 0; h < 8; ++h) m[h] = sv0[h];
        }
        for (int e2 = start + 64 + lane; e2 < end; e2 += 64) {
            int s = csr_src[e2];
            float4 x0 = *(const float4*)(a2 + (size_t)s * 8);
            float4 x1 = *(const float4*)(a2 + (size_t)s * 8 + 4);
            m[0] = fmaxf(m[0], leaky(a1v[0] + x0.x)); m[1] = fmaxf(m[1], leaky(a1v[1] + x0.y));
            m[2] = fmaxf(m[2], leaky(a1v[2] + x0.z)); m[3] = fmaxf(m[3], leaky(a1v[3] + x0.w));
            m[4] = fmaxf(m[4], leaky(a1v[4] + x1.x)); m[5] = fmaxf(m[5], leaky(a1v[5] + x1.y));
            m[6] = fmaxf(m[6], leaky(a1v[6] + x1.z)); m[7] = fmaxf(m[7], leaky(a1v[7] + x1.w));
        }
#pragma unroll
        for (int h = 0; h < 8; ++h)
#pragma unroll
            for (int off = 32; off > 0; off >>= 1)
                m[h] = fmaxf(m[h], __shfl_xor(m[h], off));
    }

    // ---- pass 2: per-chunk weights -> LDS table; gather + accumulate
    float denom[8];
    float acc[16];
#pragma unroll
    for (int h = 0; h < 8; ++h) denom[h] = 0.f;
#pragma unroll
    for (int i = 0; i < 16; ++i) acc[i] = 0.f;

    int pb = 0;
    for (int base = start; base < end; base += 64, pb ^= 1) {
        int e = base + lane;
        int cnt = min(64, end - base);
        float w[8];
        int sidx = 0;
        if (base == start) {
            sidx = sidx0;
            if (e < end) {
#pragma unroll
                for (int h = 0; h < 8; ++h) w[h] = expf(sv0[h] - m[h]);
            } else {
#pragma unroll
                for (int h = 0; h < 8; ++h) w[h] = 0.f;
            }
        } else if (e < end) {
            sidx = csr_src[e];
            float4 x0 = *(const float4*)(a2 + (size_t)sidx * 8);
            float4 x1 = *(const float4*)(a2 + (size_t)sidx * 8 + 4);
            w[0] = expf(leaky(a1v[0] + x0.x) - m[0]); w[1] = expf(leaky(a1v[1] + x0.y) - m[1]);
            w[2] = expf(leaky(a1v[2] + x0.z) - m[2]); w[3] = expf(leaky(a1v[3] + x0.w) - m[3]);
            w[4] = expf(leaky(a1v[4] + x1.x) - m[4]); w[5] = expf(leaky(a1v[5] + x1.y) - m[5]);
            w[6] = expf(leaky(a1v[6] + x1.z) - m[6]); w[7] = expf(leaky(a1v[7] + x1.w) - m[7]);
        } else {
#pragma unroll
            for (int h = 0; h < 8; ++h) w[h] = 0.f;
        }
#pragma unroll
        for (int h = 0; h < 8; ++h) denom[h] += w[h];

        *(float4*)&wtab[pb][wid][lane][0] = *(float4*)&w[0];
        *(float4*)&wtab[pb][wid][lane][4] = *(float4*)&w[4];
        stab[pb][wid][lane] = sidx;
        asm volatile("s_waitcnt lgkmcnt(0)" ::: "memory");

        const float* wrow = &wtab[pb][wid][0][0];
        const int*   srow = &stab[pb][wid][0];
        const int myh = lane >> 4;      // head for first half; second half = myh+4
        // 2 edges in flight
        for (int j = 0; j < cnt; j += 2) {
            int j1ok = (j + 1 < cnt);
            int j1 = j1ok ? j + 1 : j;
            int s0 = srow[j];
            int s1 = srow[j1];
            float w00 = wrow[j * 8 + myh];
            float w01 = wrow[j * 8 + 4 + myh];
            float w10 = j1ok ? wrow[j1 * 8 + myh] : 0.f;
            float w11 = j1ok ? wrow[j1 * 8 + 4 + myh] : 0.f;
            const unsigned short* f0 = ft + (size_t)s0 * 1024;
            const unsigned short* f1 = ft + (size_t)s1 * 1024;
            uint4 v00 = *(const uint4*)(f0 + lane * 8);
            uint4 v01 = *(const uint4*)(f0 + 512 + lane * 8);
            uint4 v10 = *(const uint4*)(f1 + lane * 8);
            uint4 v11 = *(const uint4*)(f1 + 512 + lane * 8);
            acc[0]  += w00 * bflo(v00.x); acc[1]  += w00 * bfhi(v00.x);
            acc[2]  += w00 * bflo(v00.y); acc[3]  += w00 * bfhi(v00.y);
            acc[4]  += w00 * bflo(v00.z); acc[5]  += w00 * bfhi(v00.z);
            acc[6]  += w00 * bflo(v00.w); acc[7]  += w00 * bfhi(v00.w);
            acc[8]  += w01 * bflo(v01.x); acc[9]  += w01 * bfhi(v01.x);
            acc[10] += w01 * bflo(v01.y); acc[11] += w01 * bfhi(v01.y);
            acc[12] += w01 * bflo(v01.z); acc[13] += w01 * bfhi(v01.z);
            acc[14] += w01 * bflo(v01.w); acc[15] += w01 * bfhi(v01.w);
            acc[0]  += w10 * bflo(v10.x); acc[1]  += w10 * bfhi(v10.x);
            acc[2]  += w10 * bflo(v10.y); acc[3]  += w10 * bfhi(v10.y);
            acc[4]  += w10 * bflo(v10.z); acc[5]  += w10 * bfhi(v10.z);
            acc[6]  += w10 * bflo(v10.w); acc[7]  += w10 * bfhi(v10.w);
            acc[8]  += w11 * bflo(v11.x); acc[9]  += w11 * bfhi(v11.x);
            acc[10] += w11 * bflo(v11.y); acc[11] += w11 * bfhi(v11.y);
            acc[12] += w11 * bflo(v11.z); acc[13] += w11 * bfhi(v11.z);
            acc[14] += w11 * bflo(v11.w); acc[15] += w11 * bfhi(v11.w);
        }
    }

    // reduce denominators across wave
#pragma unroll
    for (int h = 0; h < 8; ++h)
#pragma unroll
        for (int off = 32; off > 0; off >>= 1)
            denom[h] += __shfl_xor(denom[h], off);

    // select this lane's two head-denominators: myh = lane>>4, myh+4
    float t01 = (lane & 16) ? denom[1] : denom[0];
    float t23 = (lane & 16) ? denom[3] : denom[2];
    float dlo = (lane & 32) ? t23 : t01;
    float t45 = (lane & 16) ? denom[5] : denom[4];
    float t67 = (lane & 16) ? denom[7] : denom[6];
    float dhi = (lane & 32) ? t67 : t45;
    float inv0 = 1.f / dlo;
    float inv1 = 1.f / dhi;

    unsigned pk[4];
#pragma unroll
    for (int u = 0; u < 4; ++u) {
        float r0 = acc[2 * u] * inv0, r1 = acc[2 * u + 1] * inv0;
        r0 = (r0 > 0.f) ? r0 : expm1f(r0);
        r1 = (r1 > 0.f) ? r1 : expm1f(r1);
        pk[u] = (unsigned)f2bf(r0) | ((unsigned)f2bf(r1) << 16);
    }
    *(uint4*)(op + lane * 8) = make_uint4(pk[0], pk[1], pk[2], pk[3]);
#pragma unroll
    for (int u = 0; u < 4; ++u) {
        float r0 = acc[8 + 2 * u] * inv1, r1 = acc[8 + 2 * u + 1] * inv1;
        r0 = (r0 > 0.f) ? r0 : expm1f(r0);
        r1 = (r1 > 0.f) ? r1 : expm1f(r1);
        pk[u] = (unsigned)f2bf(r0) | ((unsigned)f2bf(r1) << 16);
    }
    *(uint4*)(op + 512 + lane * 8) = make_uint4(pk[0], pk[1], pk[2], pk[3]);
}

// ---------------- final aggregate: H=1, Dh=64, bf16 in [N][64], fp32 out ----------------
__global__ __launch_bounds__(256) void k_aggregate_final(
    const unsigned short* __restrict__ ft, const float* __restrict__ a1,
    const float* __restrict__ a2, const int* __restrict__ indptr,
    const int* __restrict__ csr_src, float* __restrict__ outp)
{
    int n = blockIdx.x * 4 + (threadIdx.x >> 6);
    int lane = threadIdx.x & 63;
    if (n >= N_NODES) return;
    size_t obase = (size_t)n * 64;
    int start = indptr[n], end = indptr[n + 1];

    if (end <= start) {
        if (lane < 32) *(float2*)(outp + obase + 2 * lane) = make_float2(0.f, 0.f);
        return;
    }
    float a1v = a1[n];

    int sidx0 = 0; float sv0 = 0.f;
    float m = -INFINITY;
    {
        int e = start + lane;
        if (e < end) {
            sidx0 = csr_src[e];
            sv0 = leaky(a1v + a2[sidx0]);
            m = sv0;
        }
        for (int e2 = start + 64 + lane; e2 < end; e2 += 64)
            m = fmaxf(m, leaky(a1v + a2[csr_src[e2]]));
#pragma unroll
        for (int off = 32; off > 0; off >>= 1) m = fmaxf(m, __shfl_xor(m, off));
    }

    float denom = 0.f, acc0 = 0.f, acc1 = 0.f;
    int half = lane >> 5, idx = lane & 31;
    for (int base = start; base < end; base += 64) {
        int e = base + lane;
        float wgt = 0.f;
        int sidx = sidx0;
        if (base == start) {
            if (e < end) wgt = expf(sv0 - m);
        } else if (e < end) {
            sidx = csr_src[e];
            wgt = expf(leaky(a1v + a2[sidx]) - m);
        }
        denom += wgt;
        int cnt = min(64, end - base);
        for (int i = 0; i < cnt; i += 4) {
            int j0 = i + half, j1 = i + 2 + half;
            int jc0 = (j0 < cnt) ? j0 : (cnt - 1);
            int jc1 = (j1 < cnt) ? j1 : (cnt - 1);
            float w0 = __shfl(wgt, jc0); int s0 = __shfl(sidx, jc0);
            float w1 = __shfl(wgt, jc1); int s1 = __shfl(sidx, jc1);
            if (j0 >= cnt) w0 = 0.f;
            if (j1 >= cnt) w1 = 0.f;
            unsigned v0 = *(const unsigned*)(ft + (size_t)s0 * 64 + 2 * idx);
            unsigned v1 = *(const unsigned*)(ft + (size_t)s1 * 64 + 2 * idx);
            acc0 += w0 * bflo(v0) + w1 * bflo(v1);
            acc1 += w0 * bfhi(v0) + w1 * bfhi(v1);
        }
    }
#pragma unroll
    for (int off = 32; off > 0; off >>= 1) denom += __shfl_xor(denom, off);
    float inv = 1.f / denom;

    acc0 += __shfl_xor(acc0, 32);
    acc1 += __shfl_xor(acc1, 32);
    float r0 = acc0 * inv, r1 = acc1 * inv;
    r0 = (r0 > 0.f) ? r0 : expm1f(r0);
    r1 = (r1 > 0.f) ? r1 : expm1f(r1);
    if (lane < 32)
        *(float2*)(outp + obase + 2 * lane) = make_float2(r0, r1);
}

// ---------------- launch ----------------
extern "C" void kernel_launch(void* const* d_in, const int* in_sizes, int n_in,
                              void* d_out, int out_size, void* d_ws, size_t ws_size,
                              hipStream_t stream) {
    const float* features = (const float*)d_in[0];
    const int*   src      = (const int*)d_in[1];
    const int*   dst      = (const int*)d_in[2];
    const float* W0  = (const float*)d_in[3];
    const float* b0  = (const float*)d_in[4];
    const float* al0 = (const float*)d_in[5];
    const float* alb0= (const float*)d_in[6];
    const float* ar0 = (const float*)d_in[7];
    const float* arb0= (const float*)d_in[8];
    const float* W1  = (const float*)d_in[9];
    const float* b1  = (const float*)d_in[10];
    const float* al1 = (const float*)d_in[11];
    const float* alb1= (const float*)d_in[12];
    const float* ar1 = (const float*)d_in[13];
    const float* arb1= (const float*)d_in[14];
    const float* Wf  = (const float*)d_in[15];
    const float* bff = (const float*)d_in[16];
    const float* alf = (const float*)d_in[17];
    const float* albf= (const float*)d_in[18];
    const float* arf = (const float*)d_in[19];
    const float* arbf= (const float*)d_in[20];
    float* out = (float*)d_out;

    // workspace carve
    char* wp = (char*)d_ws;
    unsigned short* ft16  = (unsigned short*)wp;  wp += (size_t)N_NODES * 1024 * 2;  // [N][1024] (or [N][64] final)
    unsigned short* xb16  = (unsigned short*)wp;  wp += (size_t)N_NODES * 1024 * 2;  // [N][1024]
    unsigned short* feat16= (unsigned short*)wp;  wp += (size_t)N_NODES * 512 * 2;
    unsigned short* w0t   = (unsigned short*)wp;  wp += (size_t)N_HEADS * D_HID * D_IN * 2;
    unsigned short* w1t   = (unsigned short*)wp;  wp += (size_t)N_HEADS * D_HID * 1024 * 2;
    unsigned short* wft   = (unsigned short*)wp;  wp += (size_t)N_CLS * 1024 * 2;
    float* a1             = (float*)wp;           wp += (size_t)N_NODES * N_HEADS * 4;
    float* a2             = (float*)wp;           wp += (size_t)N_NODES * N_HEADS * 4;
    int* counts = (int*)wp;                       wp += (size_t)N_NODES * 4;
    int* indptr = (int*)wp;                       wp += (size_t)(N_NODES + 1) * 4;
    int* cursor = (int*)wp;                       wp += (size_t)N_NODES * 4;
    int* csr    = (int*)wp;

    // ---- CSR build
    k_zero<<<(N_NODES + 255) / 256, 256, 0, stream>>>(counts, N_NODES);
    k_count<<<(N_EDGES + 255) / 256, 256, 0, stream>>>(dst, counts, N_EDGES);
    k_scan<<<1, 1024, 0, stream>>>(counts, indptr, cursor, N_NODES);
    k_scatter<<<(N_EDGES + 255) / 256, 256, 0, stream>>>(src, dst, cursor, csr, N_EDGES);

    // ---- conversions
    k_cvtA<<<(N_NODES * D_IN / 4 + 255) / 256, 256, 0, stream>>>(features, feat16, N_NODES * D_IN / 4);
    k_cvtW<<<dim3(D_IN / 64, D_HID / 64, N_HEADS), 256, 0, stream>>>(W0, w0t, D_IN, D_HID);
    k_cvtW<<<dim3(1024 / 64, D_HID / 64, N_HEADS), 256, 0, stream>>>(W1, w1t, 1024, D_HID);
    k_cvtW<<<dim3(1024 / 64, N_CLS / 64, 1), 256, 0, stream>>>(Wf, wft, 1024, N_CLS);

    const int gm = (N_NODES + 127) / 128;           // 157
    int nodeBlocks = (N_NODES + 3) / 4;             // 5000

    // ---- layer 0: feat16 [N,512] -> ft16 [N][1024] + a1/a2 (fused)
    k_gemm_fused<<<dim3(gm, 1, N_HEADS / 2), 256, 0, stream>>>(
        feat16, w0t, b0, al0, alb0, ar0, arb0, ft16, a1, a2, N_NODES, D_IN);
    k_aggregate_ah<<<nodeBlocks, 256, 0, stream>>>(ft16, a1, a2, indptr, csr, xb16);

    // ---- layer 1: xb16 [N,1024] -> ft16 [N][1024] + a1/a2 (fused)
    k_gemm_fused<<<dim3(gm, 1, N_HEADS / 2), 256, 0, stream>>>(
        xb16, w1t, b1, al1, alb1, ar1, arb1, ft16, a1, a2, N_NODES, 1024);
    k_aggregate_ah<<<nodeBlocks, 256, 0, stream>>>(ft16, a1, a2, indptr, csr, xb16);

    // ---- final layer: xb16 [N,1024] -> ft16 [N,64] -> out [N,64]
    k_gemm_bf16<64><<<dim3(gm, 1, 1), 256, 0, stream>>>(
        xb16, wft, bff, ft16, N_NODES, 1024, N_CLS);
    k_alogit<<<nodeBlocks, 256, 0, stream>>>(ft16, alf, albf, arf, arbf, a1, a2, 1, N_CLS);
    k_aggregate_final<<<nodeBlocks, 256, 0, stream>>>(ft16, a1, a2, indptr, csr, out);
}

// Round 9
// 556.776 us; speedup vs baseline: 1.1866x; 1.1076x over previous
//
#include <hip/hip_runtime.h>
#include <math.h>

// Problem constants (match reference)
#define N_NODES 20000
#define N_EDGES 320000
#define D_IN    512
#define D_HID   128
#define N_HEADS 8
#define N_CLS   64

typedef __bf16 bf16x8 __attribute__((ext_vector_type(8)));
typedef float  f32x4  __attribute__((ext_vector_type(4)));

__device__ __forceinline__ float leaky(float x) { return fmaxf(x, 0.01f * x); }

// fp32 -> bf16 round-to-nearest-even
__device__ __forceinline__ unsigned short f2bf(float f) {
    unsigned u = __float_as_uint(f);
    return (unsigned short)((u + 0x7FFFu + ((u >> 16) & 1u)) >> 16);
}
__device__ __forceinline__ float bflo(unsigned v) { return __uint_as_float(v << 16); }
__device__ __forceinline__ float bfhi(unsigned v) { return __uint_as_float(v & 0xffff0000u); }

__device__ __forceinline__ void gl_lds16(const void* g, void* l) {
    __builtin_amdgcn_global_load_lds((const __attribute__((address_space(1))) void*)g,
                                     (__attribute__((address_space(3))) void*)l, 16, 0, 0);
}

// ---------------- CSR build (rebuilt every call) ----------------
__global__ void k_zero(int* __restrict__ p, int n) {
    int i = blockIdx.x * blockDim.x + threadIdx.x;
    if (i < n) p[i] = 0;
}

__global__ void k_count(const int* __restrict__ dst, int* __restrict__ counts, int e) {
    int i = blockIdx.x * blockDim.x + threadIdx.x;
    if (i < e) atomicAdd(&counts[dst[i]], 1);
}

__global__ void k_scan(const int* __restrict__ counts, int* __restrict__ indptr,
                       int* __restrict__ cursor, int n) {
    __shared__ int sdata[1024];
    __shared__ int srun;
    int t = threadIdx.x;
    if (t == 0) srun = 0;
    __syncthreads();
    for (int base = 0; base < n; base += 1024) {
        int idx = base + t;
        int v = (idx < n) ? counts[idx] : 0;
        sdata[t] = v;
        __syncthreads();
        for (int off = 1; off < 1024; off <<= 1) {
            int x = (t >= off) ? sdata[t - off] : 0;
            __syncthreads();
            sdata[t] += x;
            __syncthreads();
        }
        int incl = sdata[t];
        int run = srun;
        if (idx < n) {
            indptr[idx] = run + incl - v;
            cursor[idx] = run + incl - v;
        }
        __syncthreads();
        if (t == 1023) srun = run + incl;
        __syncthreads();
    }
    if (t == 0) indptr[n] = srun;
}

__global__ void k_scatter(const int* __restrict__ src, const int* __restrict__ dst,
                          int* __restrict__ cursor, int* __restrict__ csr_src, int e) {
    int i = blockIdx.x * blockDim.x + threadIdx.x;
    if (i < e) {
        int pos = atomicAdd(&cursor[dst[i]], 1);
        csr_src[pos] = src[i];
    }
}

// ---------------- conversions ----------------
__global__ void k_cvtA(const float* __restrict__ in, unsigned short* __restrict__ out, int n4) {
    int i = blockIdx.x * blockDim.x + threadIdx.x;
    if (i < n4) {
        float4 v = ((const float4*)in)[i];
        unsigned long long pk =
            (unsigned long long)f2bf(v.x) | ((unsigned long long)f2bf(v.y) << 16) |
            ((unsigned long long)f2bf(v.z) << 32) | ((unsigned long long)f2bf(v.w) << 48);
        *(unsigned long long*)(out + (size_t)i * 4) = pk;
    }
}

// W [h][K][Nf] fp32 -> Wt [h][Nf][K] bf16
__global__ void k_cvtW(const float* __restrict__ W, unsigned short* __restrict__ Wt,
                       int K, int Nf) {
    __shared__ float t[64][65];
    int k0 = blockIdx.x * 64, n0 = blockIdx.y * 64, h = blockIdx.z;
    const float* Wh = W + (size_t)h * K * Nf;
    unsigned short* Wth = Wt + (size_t)h * K * Nf;
    int tx = threadIdx.x & 63, ty = threadIdx.x >> 6;
#pragma unroll
    for (int i = 0; i < 16; ++i) {
        int k = ty + i * 4;
        t[k][tx] = Wh[(size_t)(k0 + k) * Nf + n0 + tx];
    }
    __syncthreads();
#pragma unroll
    for (int i = 0; i < 16; ++i) {
        int n = ty + i * 4;
        Wth[(size_t)(n0 + n) * K + k0 + tx] = f2bf(t[tx][n]);
    }
}

// ---------------- fused bf16 MFMA GEMM (1 head per z-block) + alogit epilogue ----
// BM=128, BN=128, BK=64, 4 waves: wm=wid>>1 (64-row strip), wn=wid&1 (64-col half).
// SWAPPED-OPERAND MFMA: accT[ni][mi] = mfma(bv, av, .) computes C^T fragments, so
// each thread holds 4 CONTIGUOUS n-cols at fixed m -> 8B packed ft stores and a
// cheap a1/a2 reduction (shfl 16,32 + LDS cross-wave combine).
// Outputs: ft [N][1024] bf16 (head h at cols h*128..); a1/a2 [N][8] fp32.
__global__ __launch_bounds__(256) void k_gemm_fused(
    const unsigned short* __restrict__ A, const unsigned short* __restrict__ Bt,
    const float* __restrict__ bias, const float* __restrict__ al,
    const float* __restrict__ alb, const float* __restrict__ ar,
    const float* __restrict__ arb, unsigned short* __restrict__ C,
    float* __restrict__ a1, float* __restrict__ a2, int M, int K)
{
    constexpr int BM = 128, BK = 64, BN = 128;
    __shared__ unsigned short As[BM * BK];   // 16 KB
    __shared__ unsigned short Bs[BN * BK];   // 16 KB
    __shared__ float p1[4][64], p2[4][64];   // 2 KB cross-wave a1/a2 partials

    const int tid  = threadIdx.x;
    const int lane = tid & 63;
    const int wid  = tid >> 6;
    const int wm   = wid >> 1;      // 0..1: 64-row strip
    const int wn   = wid & 1;       // 0..1: 64-col half
    const int m0   = blockIdx.x * BM;
    const int h    = blockIdx.z;

    const unsigned short* Bth = Bt + (size_t)h * 128 * K;
    const int rsub = lane & 15;
    const int rhi  = lane >> 4;
    const int wbase = tid & ~63;

    f32x4 accT[4][4];   // [ni][mi]; thread holds C[m=..+rsub][n=..+rhi*4+r]
#pragma unroll
    for (int i = 0; i < 4; ++i)
#pragma unroll
        for (int j = 0; j < 4; ++j) accT[i][j] = (f32x4){0.f, 0.f, 0.f, 0.f};

    for (int k0 = 0; k0 < K; k0 += BK) {
        // A: 128 rows x 64 bf16, 4 passes
#pragma unroll
        for (int p = 0; p < 4; ++p) {
            int o    = (p * 256 + tid) * 16;
            int row  = o >> 7;
            int icol = (o & 127) ^ ((row & 7) << 4);
            int grow = m0 + row; if (grow > M - 1) grow = M - 1;
            gl_lds16(A + (size_t)grow * K + k0 + (icol >> 1),
                     (void*)((char*)As + (p * 256 + wbase) * 16));
        }
        // B: 128 rows x 64 bf16, 4 passes
#pragma unroll
        for (int p = 0; p < 4; ++p) {
            int o    = (p * 256 + tid) * 16;
            int row  = o >> 7;
            int icol = (o & 127) ^ ((row & 7) << 4);
            gl_lds16(Bth + (size_t)row * K + k0 + (icol >> 1),
                     (void*)((char*)Bs + (p * 256 + wbase) * 16));
        }
        __syncthreads();

#pragma unroll
        for (int q = 0; q < 2; ++q) {
            bf16x8 av[4], bv[4];
#pragma unroll
            for (int mi = 0; mi < 4; ++mi) {
                int row  = wm * 64 + mi * 16 + rsub;
                int icol = (q * 64 + rhi * 16) ^ ((row & 7) << 4);
                av[mi] = *(const bf16x8*)((const char*)As + row * 128 + icol);
            }
#pragma unroll
            for (int ni = 0; ni < 4; ++ni) {
                int row  = wn * 64 + ni * 16 + rsub;
                int icol = (q * 64 + rhi * 16) ^ ((row & 7) << 4);
                bv[ni] = *(const bf16x8*)((const char*)Bs + row * 128 + icol);
            }
            // swapped operands: compute C^T fragments
#pragma unroll
            for (int ni = 0; ni < 4; ++ni)
#pragma unroll
                for (int mi = 0; mi < 4; ++mi)
                    accT[ni][mi] = __builtin_amdgcn_mfma_f32_16x16x32_bf16(
                        bv[ni], av[mi], accT[ni][mi], 0, 0, 0);
        }
        __syncthreads();
    }

    // bias add (a1/a2 must include bias: ft = xW + b); n = wn*64 + ni*16 + rhi*4 + r
    float4 al4[4], ar4[4];
#pragma unroll
    for (int ni = 0; ni < 4; ++ni) {
        int nb = wn * 64 + ni * 16 + rhi * 4;
        float4 b4 = *(const float4*)&bias[h * 128 + nb];
        al4[ni] = *(const float4*)&al[h * 128 + nb];
        ar4[ni] = *(const float4*)&ar[h * 128 + nb];
#pragma unroll
        for (int mi = 0; mi < 4; ++mi) {
            accT[ni][mi][0] += b4.x; accT[ni][mi][1] += b4.y;
            accT[ni][mi][2] += b4.z; accT[ni][mi][3] += b4.w;
        }
    }

    // store ft: 4 contiguous bf16 (8B) per frag per thread
#pragma unroll
    for (int mi = 0; mi < 4; ++mi) {
        int m = m0 + wm * 64 + mi * 16 + rsub;
        if (m >= M) continue;
        unsigned short* cp = C + (size_t)m * 1024 + h * 128 + wn * 64 + rhi * 4;
#pragma unroll
        for (int ni = 0; ni < 4; ++ni) {
            unsigned long long pk =
                (unsigned long long)f2bf(accT[ni][mi][0]) |
                ((unsigned long long)f2bf(accT[ni][mi][1]) << 16) |
                ((unsigned long long)f2bf(accT[ni][mi][2]) << 32) |
                ((unsigned long long)f2bf(accT[ni][mi][3]) << 48);
            *(unsigned long long*)(cp + ni * 16) = pk;
        }
    }

    // a1/a2 partials: dot over this thread's 16 n-values, reduce over rhi (16,32),
    // stage per-wave partials in LDS, combine across the two col-half waves.
#pragma unroll
    for (int mi = 0; mi < 4; ++mi) {
        float s1 = 0.f, s2 = 0.f;
#pragma unroll
        for (int ni = 0; ni < 4; ++ni) {
            s1 += accT[ni][mi][0] * al4[ni].x + accT[ni][mi][1] * al4[ni].y
                + accT[ni][mi][2] * al4[ni].z + accT[ni][mi][3] * al4[ni].w;
            s2 += accT[ni][mi][0] * ar4[ni].x + accT[ni][mi][1] * ar4[ni].y
                + accT[ni][mi][2] * ar4[ni].z + accT[ni][mi][3] * ar4[ni].w;
        }
        s1 += __shfl_xor(s1, 16); s1 += __shfl_xor(s1, 32);
        s2 += __shfl_xor(s2, 16); s2 += __shfl_xor(s2, 32);
        if (rhi == 0) {
            p1[wid][mi * 16 + rsub] = s1;
            p2[wid][mi * 16 + rsub] = s2;
        }
    }
    __syncthreads();
    if (wn == 0 && rhi == 0) {
        float albv = alb[h], arbv = arb[h];
#pragma unroll
        for (int mi = 0; mi < 4; ++mi) {
            int rl = mi * 16 + rsub;
            int row = m0 + wm * 64 + rl;
            if (row < M) {
                a1[row * 8 + h] = p1[wm * 2][rl] + p1[wm * 2 + 1][rl] + albv;
                a2[row * 8 + h] = p2[wm * 2][rl] + p2[wm * 2 + 1][rl] + arbv;
            }
        }
    }
}

// ---------------- final-layer GEMM (BN=64, unfused) ----------------
template<int BN>
__global__ __launch_bounds__(256) void k_gemm_bf16(
    const unsigned short* __restrict__ A, const unsigned short* __restrict__ Bt,
    const float* __restrict__ bias, unsigned short* __restrict__ C,
    int M, int K, int ldc)
{
    constexpr int BM = 128, BK = 64;
    constexpr int WN    = 1;
    constexpr int MFRAG = 2;
    constexpr int NFRAG = 4;

    __shared__ unsigned short As[BM * BK];
    __shared__ unsigned short Bs[BN * BK];

    const int tid  = threadIdx.x;
    const int lane = tid & 63;
    const int wid  = tid >> 6;
    const int wm   = wid / WN;
    const int wn   = wid % WN;
    const int m0   = blockIdx.x * BM;

    const int rsub = lane & 15;
    const int rhi  = lane >> 4;
    const int wbase = tid & ~63;

    f32x4 acc[MFRAG][NFRAG];
#pragma unroll
    for (int i = 0; i < MFRAG; ++i)
#pragma unroll
        for (int j = 0; j < NFRAG; ++j) acc[i][j] = (f32x4){0.f, 0.f, 0.f, 0.f};

    for (int k0 = 0; k0 < K; k0 += BK) {
#pragma unroll
        for (int p = 0; p < 4; ++p) {
            int o    = (p * 256 + tid) * 16;
            int row  = o >> 7;
            int icol = (o & 127) ^ ((row & 7) << 4);
            int grow = m0 + row; if (grow > M - 1) grow = M - 1;
            gl_lds16(A + (size_t)grow * K + k0 + (icol >> 1),
                     (void*)((char*)As + (p * 256 + wbase) * 16));
        }
#pragma unroll
        for (int p = 0; p < BN / 32; ++p) {
            int o    = (p * 256 + tid) * 16;
            int row  = o >> 7;
            int icol = (o & 127) ^ ((row & 7) << 4);
            gl_lds16(Bt + (size_t)row * K + k0 + (icol >> 1),
                     (void*)((char*)Bs + (p * 256 + wbase) * 16));
        }
        __syncthreads();

        bf16x8 av[2][MFRAG], bv[2][NFRAG];
#pragma unroll
        for (int q = 0; q < 2; ++q) {
#pragma unroll
            for (int mi = 0; mi < MFRAG; ++mi) {
                int row  = wm * (MFRAG * 16) + mi * 16 + rsub;
                int icol = (q * 64 + rhi * 16) ^ ((row & 7) << 4);
                av[q][mi] = *(const bf16x8*)((const char*)As + row * 128 + icol);
            }
#pragma unroll
            for (int ni = 0; ni < NFRAG; ++ni) {
                int row  = wn * (NFRAG * 16) + ni * 16 + rsub;
                int icol = (q * 64 + rhi * 16) ^ ((row & 7) << 4);
                bv[q][ni] = *(const bf16x8*)((const char*)Bs + row * 128 + icol);
            }
        }
#pragma unroll
        for (int q = 0; q < 2; ++q)
#pragma unroll
            for (int mi = 0; mi < MFRAG; ++mi)
#pragma unroll
                for (int ni = 0; ni < NFRAG; ++ni)
                    acc[mi][ni] = __builtin_amdgcn_mfma_f32_16x16x32_bf16(
                        av[q][mi], bv[q][ni], acc[mi][ni], 0, 0, 0);
        __syncthreads();
    }

#pragma unroll
    for (int ni = 0; ni < NFRAG; ++ni) {
        int col  = wn * (NFRAG * 16) + ni * 16 + rsub;
        float bvv = bias[col];
#pragma unroll
        for (int mi = 0; mi < MFRAG; ++mi) {
            int rowb = m0 + wm * (MFRAG * 16) + mi * 16 + rhi * 4;
#pragma unroll
            for (int r = 0; r < 4; ++r) {
                int row = rowb + r;
                if (row < M) C[(size_t)row * ldc + col] = f2bf(acc[mi][ni][r] + bvv);
            }
        }
    }
}

// ---------------- per-node attention logits (final layer only) ----------------
__global__ __launch_bounds__(256) void k_alogit(
    const unsigned short* __restrict__ ft, const float* __restrict__ al,
    const float* __restrict__ alb, const float* __restrict__ ar,
    const float* __restrict__ arb, float* __restrict__ a1,
    float* __restrict__ a2, int H_, int Dh)
{
    int n = blockIdx.x * 4 + (threadIdx.x >> 6);
    int lane = threadIdx.x & 63;
    if (n >= N_NODES) return;
    for (int h = 0; h < H_; ++h) {
        size_t base = ((size_t)h * N_NODES + n) * Dh;
        float s1 = 0.f, s2 = 0.f;
        for (int j0 = 2 * lane; j0 < Dh; j0 += 128) {
            unsigned v = *(const unsigned*)(ft + base + j0);
            float lo = bflo(v), hi = bfhi(v);
            float2 A = *(const float2*)(al + h * Dh + j0);
            float2 R = *(const float2*)(ar + h * Dh + j0);
            s1 += lo * A.x + hi * A.y;
            s2 += lo * R.x + hi * R.y;
        }
#pragma unroll
        for (int off = 32; off > 0; off >>= 1) {
            s1 += __shfl_xor(s1, off);
            s2 += __shfl_xor(s2, off);
        }
        if (lane == 0) {
            a1[n * H_ + h] = s1 + alb[h];
            a2[n * H_ + h] = s2 + arb[h];
        }
    }
}

// ---------------- all-heads aggregate: one wave per dst node ----------------
__global__ __launch_bounds__(256) void k_aggregate_ah(
    const unsigned short* __restrict__ ft, const float* __restrict__ a1,
    const float* __restrict__ a2, const int* __restrict__ indptr,
    const int* __restrict__ csr_src, unsigned short* __restrict__ outp)
{
    __shared__ float wtab[2][4][64][8];   // 16 KB: [parity][wave][edge][head]
    __shared__ int   stab[2][4][64];      // 2 KB

    const int wid  = threadIdx.x >> 6;
    const int lane = threadIdx.x & 63;
    int n = blockIdx.x * 4 + wid;
    if (n >= N_NODES) return;
    int start = indptr[n], end = indptr[n + 1];
    unsigned short* op = outp + (size_t)n * 1024;

    if (end <= start) {
        uint4 z = make_uint4(0, 0, 0, 0);
        *(uint4*)(op + lane * 8) = z;
        *(uint4*)(op + 512 + lane * 8) = z;
        return;
    }

    float a1v[8];
    *(float4*)&a1v[0] = *(const float4*)(a1 + n * 8);
    *(float4*)&a1v[4] = *(const float4*)(a1 + n * 8 + 4);

    // ---- pass 1: per-head segment max; cache chunk-0 logits
    float m[8], sv0[8];
    int sidx0 = 0;
#pragma unroll
    for (int h = 0; h < 8; ++h) { m[h] = -INFINITY; sv0[h] = -INFINITY; }
    {
        int e = start + lane;
        if (e < end) {
            sidx0 = csr_src[e];
            float4 x0 = *(const float4*)(a2 + (size_t)sidx0 * 8);
            float4 x1 = *(const float4*)(a2 + (size_t)sidx0 * 8 + 4);
            sv0[0] = leaky(a1v[0] + x0.x); sv0[1] = leaky(a1v[1] + x0.y);
            sv0[2] = leaky(a1v[2] + x0.z); sv0[3] = leaky(a1v[3] + x0.w);
            sv0[4] = leaky(a1v[4] + x1.x); sv0[5] = leaky(a1v[5] + x1.y);
            sv0[6] = leaky(a1v[6] + x1.z); sv0[7] = leaky(a1v[7] + x1.w);
#pragma unroll
            for (int h = 0; h < 8; ++h) m[h] = sv0[h];
        }
        for (int e2 = start + 64 + lane; e2 < end; e2 += 64) {
            int s = csr_src[e2];
            float4 x0 = *(const float4*)(a2 + (size_t)s * 8);
            float4 x1 = *(const float4*)(a2 + (size_t)s * 8 + 4);
            m[0] = fmaxf(m[0], leaky(a1v[0] + x0.x)); m[1] = fmaxf(m[1], leaky(a1v[1] + x0.y));
            m[2] = fmaxf(m[2], leaky(a1v[2] + x0.z)); m[3] = fmaxf(m[3], leaky(a1v[3] + x0.w));
            m[4] = fmaxf(m[4], leaky(a1v[4] + x1.x)); m[5] = fmaxf(m[5], leaky(a1v[5] + x1.y));
            m[6] = fmaxf(m[6], leaky(a1v[6] + x1.z)); m[7] = fmaxf(m[7], leaky(a1v[7] + x1.w));
        }
#pragma unroll
        for (int h = 0; h < 8; ++h)
#pragma unroll
            for (int off = 32; off > 0; off >>= 1)
                m[h] = fmaxf(m[h], __shfl_xor(m[h], off));
    }

    // ---- pass 2: per-chunk weights -> LDS table; gather + accumulate
    float denom[8];
    float acc[16];
#pragma unroll
    for (int h = 0; h < 8; ++h) denom[h] = 0.f;
#pragma unroll
    for (int i = 0; i < 16; ++i) acc[i] = 0.f;

    int pb = 0;
    for (int base = start; base < end; base += 64, pb ^= 1) {
        int e = base + lane;
        int cnt = min(64, end - base);
        float w[8];
        int sidx = 0;
        if (base == start) {
            sidx = sidx0;
            if (e < end) {
#pragma unroll
                for (int h = 0; h < 8; ++h) w[h] = expf(sv0[h] - m[h]);
            } else {
#pragma unroll
                for (int h = 0; h < 8; ++h) w[h] = 0.f;
            }
        } else if (e < end) {
            sidx = csr_src[e];
            float4 x0 = *(const float4*)(a2 + (size_t)sidx * 8);
            float4 x1 = *(const float4*)(a2 + (size_t)sidx * 8 + 4);
            w[0] = expf(leaky(a1v[0] + x0.x) - m[0]); w[1] = expf(leaky(a1v[1] + x0.y) - m[1]);
            w[2] = expf(leaky(a1v[2] + x0.z) - m[2]); w[3] = expf(leaky(a1v[3] + x0.w) - m[3]);
            w[4] = expf(leaky(a1v[4] + x1.x) - m[4]); w[5] = expf(leaky(a1v[5] + x1.y) - m[5]);
            w[6] = expf(leaky(a1v[6] + x1.z) - m[6]); w[7] = expf(leaky(a1v[7] + x1.w) - m[7]);
        } else {
#pragma unroll
            for (int h = 0; h < 8; ++h) w[h] = 0.f;
        }
#pragma unroll
        for (int h = 0; h < 8; ++h) denom[h] += w[h];

        *(float4*)&wtab[pb][wid][lane][0] = *(float4*)&w[0];
        *(float4*)&wtab[pb][wid][lane][4] = *(float4*)&w[4];
        stab[pb][wid][lane] = sidx;
        asm volatile("s_waitcnt lgkmcnt(0)" ::: "memory");

        const float* wrow = &wtab[pb][wid][0][0];
        const int*   srow = &stab[pb][wid][0];
        const int myh = lane >> 4;      // head for first half; second half = myh+4
        // 2 edges in flight
        for (int j = 0; j < cnt; j += 2) {
            int j1ok = (j + 1 < cnt);
            int j1 = j1ok ? j + 1 : j;
            int s0 = srow[j];
            int s1 = srow[j1];
            float w00 = wrow[j * 8 + myh];
            float w01 = wrow[j * 8 + 4 + myh];
            float w10 = j1ok ? wrow[j1 * 8 + myh] : 0.f;
            float w11 = j1ok ? wrow[j1 * 8 + 4 + myh] : 0.f;
            const unsigned short* f0 = ft + (size_t)s0 * 1024;
            const unsigned short* f1 = ft + (size_t)s1 * 1024;
            uint4 v00 = *(const uint4*)(f0 + lane * 8);
            uint4 v01 = *(const uint4*)(f0 + 512 + lane * 8);
            uint4 v10 = *(const uint4*)(f1 + lane * 8);
            uint4 v11 = *(const uint4*)(f1 + 512 + lane * 8);
            acc[0]  += w00 * bflo(v00.x); acc[1]  += w00 * bfhi(v00.x);
            acc[2]  += w00 * bflo(v00.y); acc[3]  += w00 * bfhi(v00.y);
            acc[4]  += w00 * bflo(v00.z); acc[5]  += w00 * bfhi(v00.z);
            acc[6]  += w00 * bflo(v00.w); acc[7]  += w00 * bfhi(v00.w);
            acc[8]  += w01 * bflo(v01.x); acc[9]  += w01 * bfhi(v01.x);
            acc[10] += w01 * bflo(v01.y); acc[11] += w01 * bfhi(v01.y);
            acc[12] += w01 * bflo(v01.z); acc[13] += w01 * bfhi(v01.z);
            acc[14] += w01 * bflo(v01.w); acc[15] += w01 * bfhi(v01.w);
            acc[0]  += w10 * bflo(v10.x); acc[1]  += w10 * bfhi(v10.x);
            acc[2]  += w10 * bflo(v10.y); acc[3]  += w10 * bfhi(v10.y);
            acc[4]  += w10 * bflo(v10.z); acc[5]  += w10 * bfhi(v10.z);
            acc[6]  += w10 * bflo(v10.w); acc[7]  += w10 * bfhi(v10.w);
            acc[8]  += w11 * bflo(v11.x); acc[9]  += w11 * bfhi(v11.x);
            acc[10] += w11 * bflo(v11.y); acc[11] += w11 * bfhi(v11.y);
            acc[12] += w11 * bflo(v11.z); acc[13] += w11 * bfhi(v11.z);
            acc[14] += w11 * bflo(v11.w); acc[15] += w11 * bfhi(v11.w);
        }
    }

    // reduce denominators across wave
#pragma unroll
    for (int h = 0; h < 8; ++h)
#pragma unroll
        for (int off = 32; off > 0; off >>= 1)
            denom[h] += __shfl_xor(denom[h], off);

    // select this lane's two head-denominators: myh = lane>>4, myh+4
    float t01 = (lane & 16) ? denom[1] : denom[0];
    float t23 = (lane & 16) ? denom[3] : denom[2];
    float dlo = (lane & 32) ? t23 : t01;
    float t45 = (lane & 16) ? denom[5] : denom[4];
    float t67 = (lane & 16) ? denom[7] : denom[6];
    float dhi = (lane & 32) ? t67 : t45;
    float inv0 = 1.f / dlo;
    float inv1 = 1.f / dhi;

    unsigned pk[4];
#pragma unroll
    for (int u = 0; u < 4; ++u) {
        float r0 = acc[2 * u] * inv0, r1 = acc[2 * u + 1] * inv0;
        r0 = (r0 > 0.f) ? r0 : expm1f(r0);
        r1 = (r1 > 0.f) ? r1 : expm1f(r1);
        pk[u] = (unsigned)f2bf(r0) | ((unsigned)f2bf(r1) << 16);
    }
    *(uint4*)(op + lane * 8) = make_uint4(pk[0], pk[1], pk[2], pk[3]);
#pragma unroll
    for (int u = 0; u < 4; ++u) {
        float r0 = acc[8 + 2 * u] * inv1, r1 = acc[8 + 2 * u + 1] * inv1;
        r0 = (r0 > 0.f) ? r0 : expm1f(r0);
        r1 = (r1 > 0.f) ? r1 : expm1f(r1);
        pk[u] = (unsigned)f2bf(r0) | ((unsigned)f2bf(r1) << 16);
    }
    *(uint4*)(op + 512 + lane * 8) = make_uint4(pk[0], pk[1], pk[2], pk[3]);
}

// ---------------- final aggregate: H=1, Dh=64, bf16 in [N][64], fp32 out ----------------
__global__ __launch_bounds__(256) void k_aggregate_final(
    const unsigned short* __restrict__ ft, const float* __restrict__ a1,
    const float* __restrict__ a2, const int* __restrict__ indptr,
    const int* __restrict__ csr_src, float* __restrict__ outp)
{
    int n = blockIdx.x * 4 + (threadIdx.x >> 6);
    int lane = threadIdx.x & 63;
    if (n >= N_NODES) return;
    size_t obase = (size_t)n * 64;
    int start = indptr[n], end = indptr[n + 1];

    if (end <= start) {
        if (lane < 32) *(float2*)(outp + obase + 2 * lane) = make_float2(0.f, 0.f);
        return;
    }
    float a1v = a1[n];

    int sidx0 = 0; float sv0 = 0.f;
    float m = -INFINITY;
    {
        int e = start + lane;
        if (e < end) {
            sidx0 = csr_src[e];
            sv0 = leaky(a1v + a2[sidx0]);
            m = sv0;
        }
        for (int e2 = start + 64 + lane; e2 < end; e2 += 64)
            m = fmaxf(m, leaky(a1v + a2[csr_src[e2]]));
#pragma unroll
        for (int off = 32; off > 0; off >>= 1) m = fmaxf(m, __shfl_xor(m, off));
    }

    float denom = 0.f, acc0 = 0.f, acc1 = 0.f;
    int half = lane >> 5, idx = lane & 31;
    for (int base = start; base < end; base += 64) {
        int e = base + lane;
        float wgt = 0.f;
        int sidx = sidx0;
        if (base == start) {
            if (e < end) wgt = expf(sv0 - m);
        } else if (e < end) {
            sidx = csr_src[e];
            wgt = expf(leaky(a1v + a2[sidx]) - m);
        }
        denom += wgt;
        int cnt = min(64, end - base);
        for (int i = 0; i < cnt; i += 4) {
            int j0 = i + half, j1 = i + 2 + half;
            int jc0 = (j0 < cnt) ? j0 : (cnt - 1);
            int jc1 = (j1 < cnt) ? j1 : (cnt - 1);
            float w0 = __shfl(wgt, jc0); int s0 = __shfl(sidx, jc0);
            float w1 = __shfl(wgt, jc1); int s1 = __shfl(sidx, jc1);
            if (j0 >= cnt) w0 = 0.f;
            if (j1 >= cnt) w1 = 0.f;
            unsigned v0 = *(const unsigned*)(ft + (size_t)s0 * 64 + 2 * idx);
            unsigned v1 = *(const unsigned*)(ft + (size_t)s1 * 64 + 2 * idx);
            acc0 += w0 * bflo(v0) + w1 * bflo(v1);
            acc1 += w0 * bfhi(v0) + w1 * bfhi(v1);
        }
    }
#pragma unroll
    for (int off = 32; off > 0; off >>= 1) denom += __shfl_xor(denom, off);
    float inv = 1.f / denom;

    acc0 += __shfl_xor(acc0, 32);
    acc1 += __shfl_xor(acc1, 32);
    float r0 = acc0 * inv, r1 = acc1 * inv;
    r0 = (r0 > 0.f) ? r0 : expm1f(r0);
    r1 = (r1 > 0.f) ? r1 : expm1f(r1);
    if (lane < 32)
        *(float2*)(outp + obase + 2 * lane) = make_float2(r0, r1);
}

// ---------------- launch ----------------
extern "C" void kernel_launch(void* const* d_in, const int* in_sizes, int n_in,
                              void* d_out, int out_size, void* d_ws, size_t ws_size,
                              hipStream_t stream) {
    const float* features = (const float*)d_in[0];
    const int*   src      = (const int*)d_in[1];
    const int*   dst      = (const int*)d_in[2];
    const float* W0  = (const float*)d_in[3];
    const float* b0  = (const float*)d_in[4];
    const float* al0 = (const float*)d_in[5];
    const float* alb0= (const float*)d_in[6];
    const float* ar0 = (const float*)d_in[7];
    const float* arb0= (const float*)d_in[8];
    const float* W1  = (const float*)d_in[9];
    const float* b1  = (const float*)d_in[10];
    const float* al1 = (const float*)d_in[11];
    const float* alb1= (const float*)d_in[12];
    const float* ar1 = (const float*)d_in[13];
    const float* arb1= (const float*)d_in[14];
    const float* Wf  = (const float*)d_in[15];
    const float* bff = (const float*)d_in[16];
    const float* alf = (const float*)d_in[17];
    const float* albf= (const float*)d_in[18];
    const float* arf = (const float*)d_in[19];
    const float* arbf= (const float*)d_in[20];
    float* out = (float*)d_out;

    // workspace carve
    char* wp = (char*)d_ws;
    unsigned short* ft16  = (unsigned short*)wp;  wp += (size_t)N_NODES * 1024 * 2;  // [N][1024] (or [N][64] final)
    unsigned short* xb16  = (unsigned short*)wp;  wp += (size_t)N_NODES * 1024 * 2;  // [N][1024]
    unsigned short* feat16= (unsigned short*)wp;  wp += (size_t)N_NODES * 512 * 2;
    unsigned short* w0t   = (unsigned short*)wp;  wp += (size_t)N_HEADS * D_HID * D_IN * 2;
    unsigned short* w1t   = (unsigned short*)wp;  wp += (size_t)N_HEADS * D_HID * 1024 * 2;
    unsigned short* wft   = (unsigned short*)wp;  wp += (size_t)N_CLS * 1024 * 2;
    float* a1             = (float*)wp;           wp += (size_t)N_NODES * N_HEADS * 4;
    float* a2             = (float*)wp;           wp += (size_t)N_NODES * N_HEADS * 4;
    int* counts = (int*)wp;                       wp += (size_t)N_NODES * 4;
    int* indptr = (int*)wp;                       wp += (size_t)(N_NODES + 1) * 4;
    int* cursor = (int*)wp;                       wp += (size_t)N_NODES * 4;
    int* csr    = (int*)wp;

    // ---- CSR build
    k_zero<<<(N_NODES + 255) / 256, 256, 0, stream>>>(counts, N_NODES);
    k_count<<<(N_EDGES + 255) / 256, 256, 0, stream>>>(dst, counts, N_EDGES);
    k_scan<<<1, 1024, 0, stream>>>(counts, indptr, cursor, N_NODES);
    k_scatter<<<(N_EDGES + 255) / 256, 256, 0, stream>>>(src, dst, cursor, csr, N_EDGES);

    // ---- conversions
    k_cvtA<<<(N_NODES * D_IN / 4 + 255) / 256, 256, 0, stream>>>(features, feat16, N_NODES * D_IN / 4);
    k_cvtW<<<dim3(D_IN / 64, D_HID / 64, N_HEADS), 256, 0, stream>>>(W0, w0t, D_IN, D_HID);
    k_cvtW<<<dim3(1024 / 64, D_HID / 64, N_HEADS), 256, 0, stream>>>(W1, w1t, 1024, D_HID);
    k_cvtW<<<dim3(1024 / 64, N_CLS / 64, 1), 256, 0, stream>>>(Wf, wft, 1024, N_CLS);

    const int gm = (N_NODES + 127) / 128;           // 157
    int nodeBlocks = (N_NODES + 3) / 4;             // 5000

    // ---- layer 0: feat16 [N,512] -> ft16 [N][1024] + a1/a2 (fused)
    k_gemm_fused<<<dim3(gm, 1, N_HEADS), 256, 0, stream>>>(
        feat16, w0t, b0, al0, alb0, ar0, arb0, ft16, a1, a2, N_NODES, D_IN);
    k_aggregate_ah<<<nodeBlocks, 256, 0, stream>>>(ft16, a1, a2, indptr, csr, xb16);

    // ---- layer 1: xb16 [N,1024] -> ft16 [N][1024] + a1/a2 (fused)
    k_gemm_fused<<<dim3(gm, 1, N_HEADS), 256, 0, stream>>>(
        xb16, w1t, b1, al1, alb1, ar1, arb1, ft16, a1, a2, N_NODES, 1024);
    k_aggregate_ah<<<nodeBlocks, 256, 0, stream>>>(ft16, a1, a2, indptr, csr, xb16);

    // ---- final layer: xb16 [N,1024] -> ft16 [N,64] -> out [N,64]
    k_gemm_bf16<64><<<dim3(gm, 1, 1), 256, 0, stream>>>(
        xb16, wft, bff, ft16, N_NODES, 1024, N_CLS);
    k_alogit<<<nodeBlocks, 256, 0, stream>>>(ft16, alf, albf, arf, arbf, a1, a2, 1, N_CLS);
    k_aggregate_final<<<nodeBlocks, 256, 0, stream>>>(ft16, a1, a2, indptr, csr, out);
}